// Round 19
// baseline (271.617 us; speedup 1.0000x reference)
//
#include <hip/hip_runtime.h>
#include <hip/hip_fp16.h>

#define HID 64
#define SH 9          // log2(nodes per bucket)
#define BKN 512       // nodes per bucket
#define MAXB1 256     // max buckets supported (n <= 131072)
#define NBLK 512      // edge-chunk blocks for the counting sort
typedef unsigned int u32;

// ---------------------------------------------------------------- per-(block,bucket) histogram
__global__ __launch_bounds__(256) void count_chunks(const int* __restrict__ dst,
                                                    int* __restrict__ cnt2,
                                                    int E, int nbk) {
  __shared__ int lc[MAXB1];
  const int t = threadIdx.x;
  for (int b = t; b < nbk; b += 256) lc[b] = 0;
  __syncthreads();
  const int C = (E + NBLK - 1) / NBLK;
  const int s0 = blockIdx.x * C;
  const int s1 = min(s0 + C, E);
  for (int i = s0 + t; i < s1; i += 256) atomicAdd(&lc[dst[i] >> SH], 1);
  __syncthreads();
  for (int b = t; b < nbk; b += 256)
    cnt2[(size_t)b * NBLK + blockIdx.x] = lc[b];  // bucket-major for the scan
}

// ---------------------------------------------------------------- hierarchical scan (cnt2)
__global__ __launch_bounds__(256) void scan_blocks(const int* __restrict__ v_in,
                                                   int* __restrict__ excl,
                                                   int* __restrict__ bsum, int n) {
  __shared__ int s[256];
  const int t = threadIdx.x;
  const int i = blockIdx.x * 256 + t;
  const int v = (i < n) ? v_in[i] : 0;
  s[t] = v;
  __syncthreads();
  for (int off = 1; off < 256; off <<= 1) {
    const int u = (t >= off) ? s[t - off] : 0;
    __syncthreads();
    s[t] += u;
    __syncthreads();
  }
  if (i < n) excl[i] = s[t] - v;
  if (t == 255) bsum[blockIdx.x] = s[255];
}

__global__ __launch_bounds__(512) void scan_top(int* bsum, int nb) {
  __shared__ int s[512];
  const int t = threadIdx.x;
  const int v = (t < nb) ? bsum[t] : 0;
  s[t] = v;
  __syncthreads();
  for (int off = 1; off < 512; off <<= 1) {
    const int u = (t >= off) ? s[t - off] : 0;
    __syncthreads();
    s[t] += u;
    __syncthreads();
  }
  if (t < nb) bsum[t] = s[t] - v;
}

__global__ __launch_bounds__(256) void add_offsets2(int* __restrict__ off,
                                                    const int* __restrict__ bsum,
                                                    int* __restrict__ boff,
                                                    int NE, int E, int nbk) {
  const int m = blockIdx.x * 256 + threadIdx.x;
  if (m < NE) {
    const int v = off[m] + bsum[blockIdx.x];
    off[m] = v;
    if ((m & (NBLK - 1)) == 0) boff[m >> 9] = v;  // NBLK = 512
  }
  if (m == 0) boff[nbk] = E;
}

// ---------------------------------------------------------------- fill pairs (deterministic)
// packed u32: (dstLocal<<17) | src.  512 threads: 2x TLP for the scatter.
__global__ __launch_bounds__(512) void fill_pairs(const int* __restrict__ src,
                                                  const int* __restrict__ dst,
                                                  const int* __restrict__ off,
                                                  u32* __restrict__ pairs,
                                                  int E, int nbk) {
  __shared__ int lbase[MAXB1];
  __shared__ int lrank[MAXB1];
  const int t = threadIdx.x;
  for (int b = t; b < nbk; b += 512) {
    lbase[b] = off[(size_t)b * NBLK + blockIdx.x];
    lrank[b] = 0;
  }
  __syncthreads();
  const int C = (E + NBLK - 1) / NBLK;
  const int s0 = blockIdx.x * C;
  const int s1 = min(s0 + C, E);
  for (int i = s0 + t; i < s1; i += 512) {
    const int d = dst[i];
    const int b = d >> SH;
    const int r = atomicAdd(&lrank[b], 1);
    pairs[lbase[b] + r] = ((u32)(d & (BKN - 1)) << 17) | (u32)src[i];
  }
}

// ---------------------------------------------------------------- fused CSR build
// 1024 threads/block, no LDS pair cache (phase-2 re-read is L2-hot): 4x TLP
__global__ __launch_bounds__(1024) void bucket_csr(const u32* __restrict__ pairs,
                                                   const int* __restrict__ boff,
                                                   int* __restrict__ rowptr,
                                                   float* __restrict__ dinv,
                                                   int* __restrict__ colidx,
                                                   int n, int nbk) {
  __shared__ int ldeg[BKN];
  __shared__ int lofs[BKN];
  const int bkt = blockIdx.x;
  const int t = threadIdx.x;
  if (t < BKN) ldeg[t] = 0;
  __syncthreads();
  const int beg = boff[bkt], end = boff[bkt + 1];
  const int cnt = end - beg;
  for (int e = t; e < cnt; e += 1024)
    atomicAdd(&ldeg[pairs[beg + e] >> 17], 1);
  __syncthreads();
  if (t < BKN) lofs[t] = ldeg[t];
  __syncthreads();
  for (int o = 1; o < BKN; o <<= 1) {  // Hillis-Steele inclusive scan (512 wide)
    int u = 0;
    if (t < BKN && t >= o) u = lofs[t - o];
    __syncthreads();
    if (t < BKN) lofs[t] += u;
    __syncthreads();
  }
  if (t < BKN) {
    const int v = ldeg[t];
    const int base = beg + lofs[t] - v;  // exclusive
    const int node = bkt * BKN + t;
    if (node < n) {
      rowptr[node] = base;
      dinv[node] = rsqrtf((float)(v + 1));  // +1 self-loop
    }
    ldeg[t] = base;  // reuse as absolute cursor
  }
  if (bkt == nbk - 1 && t == 0) rowptr[n] = end;  // == E
  __syncthreads();
  for (int e = t; e < cnt; e += 1024) {
    const u32 p = pairs[beg + e];  // L2-hot re-read (65KB window)
    const int pos = atomicAdd(&ldeg[p >> 17], 1);
    colidx[pos] = (int)(p & 0x1FFFF);
  }
}

// ---------------------------------------------------------------- dense transform (fp32 in)
// g[i, c] = fp16( dinv[i] * sum_k x[i,k] * W[k,c] )
// 16 rows/block, thread = (row, 4-col group): low VGPR, ~41KB LDS, 3 blocks/CU
template <int K>
__global__ __launch_bounds__(256) void gemm_nodes(const float* __restrict__ x,
                                                  const float* __restrict__ W,
                                                  const float* __restrict__ dinv,
                                                  __half* __restrict__ out) {
  __shared__ float Wl[K * 64];
  __shared__ float xl[16][K + 4];
  const int tid = threadIdx.x;
  for (int i = tid; i < K * 16; i += 256)
    reinterpret_cast<float4*>(Wl)[i] = reinterpret_cast<const float4*>(W)[i];
  const int row0 = blockIdx.x * 16;
  for (int i = tid; i < 16 * (K / 4); i += 256) {
    const int r = i / (K / 4), q = i % (K / 4);
    reinterpret_cast<float4*>(&xl[r][0])[q] =
        reinterpret_cast<const float4*>(x + (size_t)(row0 + r) * K)[q];
  }
  __syncthreads();
  const int r = tid >> 4;
  const int cg = (tid & 15) << 2;
  float4 acc = {0.f, 0.f, 0.f, 0.f};
#pragma unroll
  for (int k = 0; k < K; k += 4) {
    const float4 xv = *reinterpret_cast<const float4*>(&xl[r][k]);
    const float4 w0 = *reinterpret_cast<const float4*>(&Wl[(k + 0) * 64 + cg]);
    const float4 w1 = *reinterpret_cast<const float4*>(&Wl[(k + 1) * 64 + cg]);
    const float4 w2 = *reinterpret_cast<const float4*>(&Wl[(k + 2) * 64 + cg]);
    const float4 w3 = *reinterpret_cast<const float4*>(&Wl[(k + 3) * 64 + cg]);
    acc.x = fmaf(xv.w, w3.x, fmaf(xv.z, w2.x, fmaf(xv.y, w1.x, fmaf(xv.x, w0.x, acc.x))));
    acc.y = fmaf(xv.w, w3.y, fmaf(xv.z, w2.y, fmaf(xv.y, w1.y, fmaf(xv.x, w0.y, acc.y))));
    acc.z = fmaf(xv.w, w3.z, fmaf(xv.z, w2.z, fmaf(xv.y, w1.z, fmaf(xv.x, w0.z, acc.z))));
    acc.w = fmaf(xv.w, w3.w, fmaf(xv.z, w2.w, fmaf(xv.y, w1.w, fmaf(xv.x, w0.w, acc.w))));
  }
  const int grow = row0 + r;
  const float di = dinv[grow];
  __half2* op = reinterpret_cast<__half2*>(out + (size_t)grow * 64 + cg);
  op[0] = __floats2half2_rn(acc.x * di, acc.y * di);
  op[1] = __floats2half2_rn(acc.z * di, acc.w * di);
}

// ---------------------------------------------------------------- dense transform (fp16 in, K=64)
__global__ __launch_bounds__(256) void gemm_nodes_h(const __half* __restrict__ x,
                                                    const float* __restrict__ W,
                                                    const float* __restrict__ dinv,
                                                    __half* __restrict__ out) {
  __shared__ float Wl[64 * 64];
  __shared__ float xl[16][68];
  const int tid = threadIdx.x;
  for (int i = tid; i < 64 * 16; i += 256)
    reinterpret_cast<float4*>(Wl)[i] = reinterpret_cast<const float4*>(W)[i];
  const int row0 = blockIdx.x * 16;
  if (tid < 128) {  // 16 rows x 8 chunks of 8 fp16 (16B loads)
    const int r = tid >> 3, q = tid & 7;
    const float4 hv = *reinterpret_cast<const float4*>(
        x + (size_t)(row0 + r) * 64 + q * 8);
    const __half2* hp = reinterpret_cast<const __half2*>(&hv);
#pragma unroll
    for (int j = 0; j < 4; ++j) {
      const float2 f = __half22float2(hp[j]);
      xl[r][q * 8 + 2 * j + 0] = f.x;
      xl[r][q * 8 + 2 * j + 1] = f.y;
    }
  }
  __syncthreads();
  const int r = tid >> 4;
  const int cg = (tid & 15) << 2;
  float4 acc = {0.f, 0.f, 0.f, 0.f};
#pragma unroll
  for (int k = 0; k < 64; k += 4) {
    const float4 xv = *reinterpret_cast<const float4*>(&xl[r][k]);
    const float4 w0 = *reinterpret_cast<const float4*>(&Wl[(k + 0) * 64 + cg]);
    const float4 w1 = *reinterpret_cast<const float4*>(&Wl[(k + 1) * 64 + cg]);
    const float4 w2 = *reinterpret_cast<const float4*>(&Wl[(k + 2) * 64 + cg]);
    const float4 w3 = *reinterpret_cast<const float4*>(&Wl[(k + 3) * 64 + cg]);
    acc.x = fmaf(xv.w, w3.x, fmaf(xv.z, w2.x, fmaf(xv.y, w1.x, fmaf(xv.x, w0.x, acc.x))));
    acc.y = fmaf(xv.w, w3.y, fmaf(xv.z, w2.y, fmaf(xv.y, w1.y, fmaf(xv.x, w0.y, acc.y))));
    acc.z = fmaf(xv.w, w3.z, fmaf(xv.z, w2.z, fmaf(xv.y, w1.z, fmaf(xv.x, w0.z, acc.z))));
    acc.w = fmaf(xv.w, w3.w, fmaf(xv.z, w2.w, fmaf(xv.y, w1.w, fmaf(xv.x, w0.w, acc.w))));
  }
  const int grow = row0 + r;
  const float di = dinv[grow];
  __half2* op = reinterpret_cast<__half2*>(out + (size_t)grow * 64 + cg);
  op[0] = __floats2half2_rn(acc.x * di, acc.y * di);
  op[1] = __floats2half2_rn(acc.z * di, acc.w * di);
}

// ---------------------------------------------------------------- pull aggregation
// one wave per node, 2 edges per load (half2 rows), 16 loads in flight per half
__global__ __launch_bounds__(256) void gather_agg(const int* __restrict__ rowptr,
                                                  const int* __restrict__ colidx,
                                                  const __half2* __restrict__ g2,
                                                  const float* __restrict__ dinv,
                                                  const float* __restrict__ bias,
                                                  __half2* __restrict__ outp, int n) {
  const int lane = threadIdx.x & 63;
  const int node = (blockIdx.x * 256 + threadIdx.x) >> 6;
  if (node >= n) return;
  const int h = lane >> 5;
  const int l = lane & 31;
  const int beg = rowptr[node];
  const int end = rowptr[node + 1];
  float2 acc = {0.f, 0.f};
  int e = beg + h;
  for (; e + 30 < end; e += 32) {  // 32 edges/wave-iter
    int s[16];
#pragma unroll
    for (int j = 0; j < 16; ++j) s[j] = colidx[e + 2 * j];
    float2 v[16];
#pragma unroll
    for (int j = 0; j < 16; ++j)
      v[j] = __half22float2(g2[((u32)s[j] << 5) + (u32)l]);
#pragma unroll
    for (int j = 0; j < 16; ++j) {
      acc.x += v[j].x;
      acc.y += v[j].y;
    }
  }
  for (; e + 6 < end; e += 8) {
    const int s0 = colidx[e + 0], s1 = colidx[e + 2];
    const int s2 = colidx[e + 4], s3 = colidx[e + 6];
    const float2 v0 = __half22float2(g2[((u32)s0 << 5) + (u32)l]);
    const float2 v1 = __half22float2(g2[((u32)s1 << 5) + (u32)l]);
    const float2 v2 = __half22float2(g2[((u32)s2 << 5) + (u32)l]);
    const float2 v3 = __half22float2(g2[((u32)s3 << 5) + (u32)l]);
    acc.x += (v0.x + v1.x) + (v2.x + v3.x);
    acc.y += (v0.y + v1.y) + (v2.y + v3.y);
  }
  for (; e < end; e += 2) {
    const float2 v = __half22float2(g2[((u32)colidx[e] << 5) + (u32)l]);
    acc.x += v.x;
    acc.y += v.y;
  }
  acc.x += __shfl_xor(acc.x, 32);
  acc.y += __shfl_xor(acc.y, 32);
  const float2 sv = __half22float2(g2[((u32)node << 5) + (u32)l]);  // self-loop
  acc.x += sv.x;
  acc.y += sv.y;
  const float di = dinv[node];
  const float2 bb = reinterpret_cast<const float2*>(bias)[l];
  const float rx = fmaxf(fmaf(acc.x, di, bb.x), 0.f);
  const float ry = fmaxf(fmaf(acc.y, di, bb.y), 0.f);
  if (h == 0) outp[(size_t)node * 32 + l] = __floats2half2_rn(rx, ry);
}

// ---------------------------------------------------------------- final FC (64 -> 11, fp16 in)
// 64 rows/block: W-stage amortized over 4 row-groups
__global__ __launch_bounds__(256) void gemm_fc(const __half* __restrict__ h,
                                               const float* __restrict__ W,
                                               const float* __restrict__ b,
                                               float* __restrict__ out, int n) {
  __shared__ float Wl[772];
  __shared__ float xl[16][68];
  const int tid = threadIdx.x;
  for (int i = tid; i < 772; i += 256) Wl[i] = 0.f;
  __syncthreads();
  for (int i = tid; i < 64 * 11; i += 256) Wl[(i / 11) * 12 + (i % 11)] = W[i];
  const int row00 = blockIdx.x * 64;
  for (int rr = 0; rr < 4; ++rr) {
    const int row0 = row00 + rr * 16;
    __syncthreads();  // covers Wl fill (rr=0) and xl reuse (rr>0)
    if (tid < 128) {  // 16 rows x 8 chunks of 8 fp16
      const int r = tid >> 3, q = tid & 7;
      const int grow = row0 + r;
      if (grow < n) {
        const float4 hv = *reinterpret_cast<const float4*>(
            h + (size_t)grow * 64 + q * 8);
        const __half2* hp = reinterpret_cast<const __half2*>(&hv);
#pragma unroll
        for (int j = 0; j < 4; ++j) {
          const float2 f = __half22float2(hp[j]);
          xl[r][q * 8 + 2 * j + 0] = f.x;
          xl[r][q * 8 + 2 * j + 1] = f.y;
        }
      }
    }
    __syncthreads();
    const int r = tid >> 4, c = tid & 15;
    float acc = 0.f;
#pragma unroll
    for (int k = 0; k < 64; k += 4) {
      acc = fmaf(xl[r][k + 0], Wl[(k + 0) * 12 + c], acc);
      acc = fmaf(xl[r][k + 1], Wl[(k + 1) * 12 + c], acc);
      acc = fmaf(xl[r][k + 2], Wl[(k + 2) * 12 + c], acc);
      acc = fmaf(xl[r][k + 3], Wl[(k + 3) * 12 + c], acc);
    }
    const int grow = row0 + r;
    if (c < 11 && grow < n) out[(size_t)grow * 11 + c] = acc + b[c];
  }
}

// ---------------------------------------------------------------- launch
extern "C" void kernel_launch(void* const* d_in, const int* in_sizes, int n_in,
                              void* d_out, int out_size, void* d_ws, size_t ws_size,
                              hipStream_t stream) {
  const float* x   = (const float*)d_in[0];
  const int*   ei  = (const int*)d_in[1];   // [2, E] int32
  const float* W1  = (const float*)d_in[2];
  const float* b1  = (const float*)d_in[3];
  const float* W2  = (const float*)d_in[4];
  const float* b2  = (const float*)d_in[5];
  const float* Wfc = (const float*)d_in[6];
  const float* bfc = (const float*)d_in[7];
  float* out = (float*)d_out;

  const int n = in_sizes[0] / 128;  // 100000
  const int E = in_sizes[1] / 2;    // 3200000
  const int* src = ei;
  const int* dst = ei + E;
  const int nbk = (n + BKN - 1) >> SH;  // 196 buckets
  const int NE = nbk * NBLK;            // 100352 count entries

  char* ws = (char*)d_ws;
  size_t o = 0;
  auto alloc = [&](size_t bytes) {
    char* p = ws + o;
    o += (bytes + 255) & ~(size_t)255;
    return p;
  };
  float*  dinv   = (float*) alloc((size_t)n * 4);
  int*    rowptr = (int*)   alloc((size_t)(n + 1) * 4);
  int*    cnt2   = (int*)   alloc((size_t)NE * 4);
  int*    off    = (int*)   alloc((size_t)NE * 4);
  int*    bsum2  = (int*)   alloc(512 * 4);
  int*    boff   = (int*)   alloc((size_t)(nbk + 1) * 4);
  u32*    pairs  = (u32*)   alloc((size_t)E * 4);
  int*    colidx = (int*)   alloc((size_t)E * 4);
  __half* B0h    = (__half*)alloc((size_t)n * HID * 2);  // g fp16
  __half* B1h    = (__half*)alloc((size_t)n * HID * 2);  // h1 / h2 fp16
  if (o > ws_size) return;

  const int nb2 = (NE + 255) / 256;  // offset-scan blocks
  const int gblocks = n / 16;        // 6250 gemm blocks
  const int fcblocks = (n + 63) / 64;

  // ---- graph preprocessing (deterministic counting sort; no global atomics)
  count_chunks<<<NBLK, 256, 0, stream>>>(dst, cnt2, E, nbk);
  scan_blocks<<<nb2, 256, 0, stream>>>(cnt2, off, bsum2, NE);
  scan_top<<<1, 512, 0, stream>>>(bsum2, nb2);
  add_offsets2<<<nb2, 256, 0, stream>>>(off, bsum2, boff, NE, E, nbk);
  fill_pairs<<<NBLK, 512, 0, stream>>>(src, dst, off, pairs, E, nbk);
  bucket_csr<<<nbk, 1024, 0, stream>>>(pairs, boff, rowptr, dinv, colidx, n, nbk);

  const int pull_blocks = (n * 64 + 255) / 256;  // one wave per node

  // ---- layer 1
  gemm_nodes<128><<<gblocks, 256, 0, stream>>>(x, W1, dinv, B0h);
  gather_agg<<<pull_blocks, 256, 0, stream>>>(rowptr, colidx,
      (const __half2*)B0h, dinv, b1, (__half2*)B1h, n);

  // ---- layer 2
  gemm_nodes_h<<<gblocks, 256, 0, stream>>>(B1h, W2, dinv, B0h);
  gather_agg<<<pull_blocks, 256, 0, stream>>>(rowptr, colidx,
      (const __half2*)B0h, dinv, b2, (__half2*)B1h, n);

  // ---- FC head (fp16 activations in, 64 rows/block)
  gemm_fc<<<fcblocks, 256, 0, stream>>>(B1h, Wfc, bfc, out, n);
}

// Round 20
// 251.309 us; speedup vs baseline: 1.0808x; 1.0808x over previous
//
#include <hip/hip_runtime.h>
#include <hip/hip_fp16.h>

#define HID 64
#define SH 9          // log2(nodes per bucket)
#define BKN 512       // nodes per bucket
#define MAXB1 256     // max buckets supported (n <= 131072)
#define NBLK 512      // edge-chunk blocks for the counting sort
typedef unsigned int u32;

// ---------------------------------------------------------------- per-(block,bucket) histogram
__global__ __launch_bounds__(256) void count_chunks(const int* __restrict__ dst,
                                                    int* __restrict__ cnt2,
                                                    int E, int nbk) {
  __shared__ int lc[MAXB1];
  const int t = threadIdx.x;
  for (int b = t; b < nbk; b += 256) lc[b] = 0;
  __syncthreads();
  const int C = (E + NBLK - 1) / NBLK;
  const int s0 = blockIdx.x * C;
  const int s1 = min(s0 + C, E);
  for (int i = s0 + t; i < s1; i += 256) atomicAdd(&lc[dst[i] >> SH], 1);
  __syncthreads();
  for (int b = t; b < nbk; b += 256)
    cnt2[(size_t)b * NBLK + blockIdx.x] = lc[b];  // bucket-major for the scan
}

// ---------------------------------------------------------------- hierarchical scan (cnt2)
__global__ __launch_bounds__(256) void scan_blocks(const int* __restrict__ v_in,
                                                   int* __restrict__ excl,
                                                   int* __restrict__ bsum, int n) {
  __shared__ int s[256];
  const int t = threadIdx.x;
  const int i = blockIdx.x * 256 + t;
  const int v = (i < n) ? v_in[i] : 0;
  s[t] = v;
  __syncthreads();
  for (int off = 1; off < 256; off <<= 1) {
    const int u = (t >= off) ? s[t - off] : 0;
    __syncthreads();
    s[t] += u;
    __syncthreads();
  }
  if (i < n) excl[i] = s[t] - v;
  if (t == 255) bsum[blockIdx.x] = s[255];
}

__global__ __launch_bounds__(512) void scan_top(int* bsum, int nb) {
  __shared__ int s[512];
  const int t = threadIdx.x;
  const int v = (t < nb) ? bsum[t] : 0;
  s[t] = v;
  __syncthreads();
  for (int off = 1; off < 512; off <<= 1) {
    const int u = (t >= off) ? s[t - off] : 0;
    __syncthreads();
    s[t] += u;
    __syncthreads();
  }
  if (t < nb) bsum[t] = s[t] - v;
}

__global__ __launch_bounds__(256) void add_offsets2(int* __restrict__ off,
                                                    const int* __restrict__ bsum,
                                                    int* __restrict__ boff,
                                                    int NE, int E, int nbk) {
  const int m = blockIdx.x * 256 + threadIdx.x;
  if (m < NE) {
    const int v = off[m] + bsum[blockIdx.x];
    off[m] = v;
    if ((m & (NBLK - 1)) == 0) boff[m >> 9] = v;  // NBLK = 512
  }
  if (m == 0) boff[nbk] = E;
}

// ---------------------------------------------------------------- fill pairs (deterministic)
// packed u32: (dstLocal<<17) | src
__global__ __launch_bounds__(512) void fill_pairs(const int* __restrict__ src,
                                                  const int* __restrict__ dst,
                                                  const int* __restrict__ off,
                                                  u32* __restrict__ pairs,
                                                  int E, int nbk) {
  __shared__ int lbase[MAXB1];
  __shared__ int lrank[MAXB1];
  const int t = threadIdx.x;
  for (int b = t; b < nbk; b += 512) {
    lbase[b] = off[(size_t)b * NBLK + blockIdx.x];
    lrank[b] = 0;
  }
  __syncthreads();
  const int C = (E + NBLK - 1) / NBLK;
  const int s0 = blockIdx.x * C;
  const int s1 = min(s0 + C, E);
  for (int i = s0 + t; i < s1; i += 512) {
    const int d = dst[i];
    const int b = d >> SH;
    const int r = atomicAdd(&lrank[b], 1);
    pairs[lbase[b] + r] = ((u32)(d & (BKN - 1)) << 17) | (u32)src[i];
  }
}

// ---------------------------------------------------------------- fused CSR build (padded rows)
// Rows padded to multiples of 8: [self-loop][dg real edges][dummies -> zero-row n].
// Per-bucket padded base = boff[bkt] + bkt*BKN*8 (slack bound: +8/node max).
__global__ __launch_bounds__(1024) void bucket_csr(const u32* __restrict__ pairs,
                                                   const int* __restrict__ boff,
                                                   int* __restrict__ rowptr,
                                                   int* __restrict__ rowend,
                                                   float* __restrict__ dinv,
                                                   int* __restrict__ colidx,
                                                   int n, int nbk) {
  __shared__ int ldeg[BKN];
  __shared__ int lofs[BKN];
  const int bkt = blockIdx.x;
  const int t = threadIdx.x;
  if (t < BKN) ldeg[t] = 0;
  __syncthreads();
  const int beg = boff[bkt], end = boff[bkt + 1];
  const int cnt = end - beg;
  for (int e = t; e < cnt; e += 1024)
    atomicAdd(&ldeg[pairs[beg + e] >> 17], 1);
  __syncthreads();
  const int node = bkt * BKN + t;
  int dg = 0, pdg = 0;
  if (t < BKN) {
    dg = ldeg[t];
    pdg = (node < n) ? ((dg + 1 + 7) & ~7) : 0;  // +1 self-loop, pad to 8
    lofs[t] = pdg;
  }
  __syncthreads();
  for (int o = 1; o < BKN; o <<= 1) {  // Hillis-Steele inclusive scan (512 wide)
    int u = 0;
    if (t < BKN && t >= o) u = lofs[t - o];
    __syncthreads();
    if (t < BKN) lofs[t] += u;
    __syncthreads();
  }
  const int pbase = beg + bkt * (BKN * 8);  // padded bucket base
  if (t < BKN && node < n) {
    const int base = pbase + lofs[t] - pdg;  // exclusive
    rowptr[node] = base;
    rowend[node] = base + pdg;
    dinv[node] = rsqrtf((float)(dg + 1));
    colidx[base] = node;                              // self-loop as edge 0
    for (int j = 1 + dg; j < pdg; ++j) colidx[base + j] = n;  // zero-row pads
    ldeg[t] = base + 1;  // cursor after self-loop
  }
  __syncthreads();
  for (int e = t; e < cnt; e += 1024) {
    const u32 p = pairs[beg + e];  // L2-hot re-read
    const int pos = atomicAdd(&ldeg[p >> 17], 1);
    colidx[pos] = (int)(p & 0x1FFFF);
  }
}

// ---------------------------------------------------------------- dense transform (fp32 in)
// g[i, c] = fp16( dinv[i] * sum_k x[i,k] * W[k,c] )
template <int K>
__global__ __launch_bounds__(256) void gemm_nodes(const float* __restrict__ x,
                                                  const float* __restrict__ W,
                                                  const float* __restrict__ dinv,
                                                  __half* __restrict__ out) {
  __shared__ float Wl[K * 64];
  __shared__ float xl[16][K + 4];
  const int tid = threadIdx.x;
  for (int i = tid; i < K * 16; i += 256)
    reinterpret_cast<float4*>(Wl)[i] = reinterpret_cast<const float4*>(W)[i];
  const int row0 = blockIdx.x * 16;
  for (int i = tid; i < 16 * (K / 4); i += 256) {
    const int r = i / (K / 4), q = i % (K / 4);
    reinterpret_cast<float4*>(&xl[r][0])[q] =
        reinterpret_cast<const float4*>(x + (size_t)(row0 + r) * K)[q];
  }
  __syncthreads();
  const int r = tid >> 4;
  const int cg = (tid & 15) << 2;
  float4 acc = {0.f, 0.f, 0.f, 0.f};
#pragma unroll
  for (int k = 0; k < K; k += 4) {
    const float4 xv = *reinterpret_cast<const float4*>(&xl[r][k]);
    const float4 w0 = *reinterpret_cast<const float4*>(&Wl[(k + 0) * 64 + cg]);
    const float4 w1 = *reinterpret_cast<const float4*>(&Wl[(k + 1) * 64 + cg]);
    const float4 w2 = *reinterpret_cast<const float4*>(&Wl[(k + 2) * 64 + cg]);
    const float4 w3 = *reinterpret_cast<const float4*>(&Wl[(k + 3) * 64 + cg]);
    acc.x = fmaf(xv.w, w3.x, fmaf(xv.z, w2.x, fmaf(xv.y, w1.x, fmaf(xv.x, w0.x, acc.x))));
    acc.y = fmaf(xv.w, w3.y, fmaf(xv.z, w2.y, fmaf(xv.y, w1.y, fmaf(xv.x, w0.y, acc.y))));
    acc.z = fmaf(xv.w, w3.z, fmaf(xv.z, w2.z, fmaf(xv.y, w1.z, fmaf(xv.x, w0.z, acc.z))));
    acc.w = fmaf(xv.w, w3.w, fmaf(xv.z, w2.w, fmaf(xv.y, w1.w, fmaf(xv.x, w0.w, acc.w))));
  }
  const int grow = row0 + r;
  const float di = dinv[grow];
  __half2* op = reinterpret_cast<__half2*>(out + (size_t)grow * 64 + cg);
  op[0] = __floats2half2_rn(acc.x * di, acc.y * di);
  op[1] = __floats2half2_rn(acc.z * di, acc.w * di);
}

// ---------------------------------------------------------------- dense transform (fp16 in, K=64)
__global__ __launch_bounds__(256) void gemm_nodes_h(const __half* __restrict__ x,
                                                    const float* __restrict__ W,
                                                    const float* __restrict__ dinv,
                                                    __half* __restrict__ out) {
  __shared__ float Wl[64 * 64];
  __shared__ float xl[16][68];
  const int tid = threadIdx.x;
  for (int i = tid; i < 64 * 16; i += 256)
    reinterpret_cast<float4*>(Wl)[i] = reinterpret_cast<const float4*>(W)[i];
  const int row0 = blockIdx.x * 16;
  if (tid < 128) {  // 16 rows x 8 chunks of 8 fp16 (16B loads)
    const int r = tid >> 3, q = tid & 7;
    const float4 hv = *reinterpret_cast<const float4*>(
        x + (size_t)(row0 + r) * 64 + q * 8);
    const __half2* hp = reinterpret_cast<const __half2*>(&hv);
#pragma unroll
    for (int j = 0; j < 4; ++j) {
      const float2 f = __half22float2(hp[j]);
      xl[r][q * 8 + 2 * j + 0] = f.x;
      xl[r][q * 8 + 2 * j + 1] = f.y;
    }
  }
  __syncthreads();
  const int r = tid >> 4;
  const int cg = (tid & 15) << 2;
  float4 acc = {0.f, 0.f, 0.f, 0.f};
#pragma unroll
  for (int k = 0; k < 64; k += 4) {
    const float4 xv = *reinterpret_cast<const float4*>(&xl[r][k]);
    const float4 w0 = *reinterpret_cast<const float4*>(&Wl[(k + 0) * 64 + cg]);
    const float4 w1 = *reinterpret_cast<const float4*>(&Wl[(k + 1) * 64 + cg]);
    const float4 w2 = *reinterpret_cast<const float4*>(&Wl[(k + 2) * 64 + cg]);
    const float4 w3 = *reinterpret_cast<const float4*>(&Wl[(k + 3) * 64 + cg]);
    acc.x = fmaf(xv.w, w3.x, fmaf(xv.z, w2.x, fmaf(xv.y, w1.x, fmaf(xv.x, w0.x, acc.x))));
    acc.y = fmaf(xv.w, w3.y, fmaf(xv.z, w2.y, fmaf(xv.y, w1.y, fmaf(xv.x, w0.y, acc.y))));
    acc.z = fmaf(xv.w, w3.z, fmaf(xv.z, w2.z, fmaf(xv.y, w1.z, fmaf(xv.x, w0.z, acc.z))));
    acc.w = fmaf(xv.w, w3.w, fmaf(xv.z, w2.w, fmaf(xv.y, w1.w, fmaf(xv.x, w0.w, acc.w))));
  }
  const int grow = row0 + r;
  const float di = dinv[grow];
  __half2* op = reinterpret_cast<__half2*>(out + (size_t)grow * 64 + cg);
  op[0] = __floats2half2_rn(acc.x * di, acc.y * di);
  op[1] = __floats2half2_rn(acc.z * di, acc.w * di);
}

// ---------------------------------------------------------------- pull aggregation (padded rows)
// rows are multiples of 8 edges incl. self-loop + zero-row pads: no ragged
// tail, minimum 4 loads in flight at all times.
__global__ __launch_bounds__(256) void gather_agg(const int* __restrict__ rowptr,
                                                  const int* __restrict__ rowend,
                                                  const int* __restrict__ colidx,
                                                  const __half2* __restrict__ g2,
                                                  const float* __restrict__ dinv,
                                                  const float* __restrict__ bias,
                                                  __half2* __restrict__ outp, int n) {
  const int lane = threadIdx.x & 63;
  const int node = (blockIdx.x * 256 + threadIdx.x) >> 6;
  if (node >= n) return;
  const int h = lane >> 5;
  const int l = lane & 31;
  const int beg = rowptr[node];
  const int end = rowend[node];
  float2 acc = {0.f, 0.f};
  int e = beg + h;
  for (; e + 30 < end; e += 32) {  // 32 edges/wave-iter, 16 loads/half in flight
    int s[16];
#pragma unroll
    for (int j = 0; j < 16; ++j) s[j] = colidx[e + 2 * j];
    float2 v[16];
#pragma unroll
    for (int j = 0; j < 16; ++j)
      v[j] = __half22float2(g2[((u32)s[j] << 5) + (u32)l]);
#pragma unroll
    for (int j = 0; j < 16; ++j) {
      acc.x += v[j].x;
      acc.y += v[j].y;
    }
  }
  for (; e + 6 < end; e += 8) {  // 8-edge granularity; exact (rows % 8 == 0)
    const int s0 = colidx[e + 0], s1 = colidx[e + 2];
    const int s2 = colidx[e + 4], s3 = colidx[e + 6];
    const float2 v0 = __half22float2(g2[((u32)s0 << 5) + (u32)l]);
    const float2 v1 = __half22float2(g2[((u32)s1 << 5) + (u32)l]);
    const float2 v2 = __half22float2(g2[((u32)s2 << 5) + (u32)l]);
    const float2 v3 = __half22float2(g2[((u32)s3 << 5) + (u32)l]);
    acc.x += (v0.x + v1.x) + (v2.x + v3.x);
    acc.y += (v0.y + v1.y) + (v2.y + v3.y);
  }
  acc.x += __shfl_xor(acc.x, 32);
  acc.y += __shfl_xor(acc.y, 32);
  const float di = dinv[node];
  const float2 bb = reinterpret_cast<const float2*>(bias)[l];
  const float rx = fmaxf(fmaf(acc.x, di, bb.x), 0.f);
  const float ry = fmaxf(fmaf(acc.y, di, bb.y), 0.f);
  if (h == 0) outp[(size_t)node * 32 + l] = __floats2half2_rn(rx, ry);
}

// ---------------------------------------------------------------- final FC (64 -> 11, fp16 in)
// 64 rows/block: W-stage amortized over 4 row-groups
__global__ __launch_bounds__(256) void gemm_fc(const __half* __restrict__ h,
                                               const float* __restrict__ W,
                                               const float* __restrict__ b,
                                               float* __restrict__ out, int n) {
  __shared__ float Wl[772];
  __shared__ float xl[16][68];
  const int tid = threadIdx.x;
  for (int i = tid; i < 772; i += 256) Wl[i] = 0.f;
  __syncthreads();
  for (int i = tid; i < 64 * 11; i += 256) Wl[(i / 11) * 12 + (i % 11)] = W[i];
  const int row00 = blockIdx.x * 64;
  for (int rr = 0; rr < 4; ++rr) {
    const int row0 = row00 + rr * 16;
    __syncthreads();  // covers Wl fill (rr=0) and xl reuse (rr>0)
    if (tid < 128) {  // 16 rows x 8 chunks of 8 fp16
      const int r = tid >> 3, q = tid & 7;
      const int grow = row0 + r;
      if (grow < n) {
        const float4 hv = *reinterpret_cast<const float4*>(
            h + (size_t)grow * 64 + q * 8);
        const __half2* hp = reinterpret_cast<const __half2*>(&hv);
#pragma unroll
        for (int j = 0; j < 4; ++j) {
          const float2 f = __half22float2(hp[j]);
          xl[r][q * 8 + 2 * j + 0] = f.x;
          xl[r][q * 8 + 2 * j + 1] = f.y;
        }
      }
    }
    __syncthreads();
    const int r = tid >> 4, c = tid & 15;
    float acc = 0.f;
#pragma unroll
    for (int k = 0; k < 64; k += 4) {
      acc = fmaf(xl[r][k + 0], Wl[(k + 0) * 12 + c], acc);
      acc = fmaf(xl[r][k + 1], Wl[(k + 1) * 12 + c], acc);
      acc = fmaf(xl[r][k + 2], Wl[(k + 2) * 12 + c], acc);
      acc = fmaf(xl[r][k + 3], Wl[(k + 3) * 12 + c], acc);
    }
    const int grow = row0 + r;
    if (c < 11 && grow < n) out[(size_t)grow * 11 + c] = acc + b[c];
  }
}

// ---------------------------------------------------------------- launch
extern "C" void kernel_launch(void* const* d_in, const int* in_sizes, int n_in,
                              void* d_out, int out_size, void* d_ws, size_t ws_size,
                              hipStream_t stream) {
  const float* x   = (const float*)d_in[0];
  const int*   ei  = (const int*)d_in[1];   // [2, E] int32
  const float* W1  = (const float*)d_in[2];
  const float* b1  = (const float*)d_in[3];
  const float* W2  = (const float*)d_in[4];
  const float* b2  = (const float*)d_in[5];
  const float* Wfc = (const float*)d_in[6];
  const float* bfc = (const float*)d_in[7];
  float* out = (float*)d_out;

  const int n = in_sizes[0] / 128;  // 100000
  const int E = in_sizes[1] / 2;    // 3200000
  const int* src = ei;
  const int* dst = ei + E;
  const int nbk = (n + BKN - 1) >> SH;  // 196 buckets
  const int NE = nbk * NBLK;            // 100352 count entries

  char* ws = (char*)d_ws;
  size_t o = 0;
  auto alloc = [&](size_t bytes) {
    char* p = ws + o;
    o += (bytes + 255) & ~(size_t)255;
    return p;
  };
  float*  dinv   = (float*) alloc((size_t)n * 4);
  int*    rowptr = (int*)   alloc((size_t)n * 4);
  int*    rowend = (int*)   alloc((size_t)n * 4);
  int*    cnt2   = (int*)   alloc((size_t)NE * 4);
  int*    off    = (int*)   alloc((size_t)NE * 4);
  int*    bsum2  = (int*)   alloc(512 * 4);
  int*    boff   = (int*)   alloc((size_t)(nbk + 1) * 4);
  u32*    pairs  = (u32*)   alloc((size_t)E * 4);
  int*    colidx = (int*)   alloc(((size_t)E + (size_t)nbk * BKN * 8) * 4);
  __half* B0h    = (__half*)alloc((size_t)(n + 1) * HID * 2);  // g fp16 (+zero row)
  __half* B1h    = (__half*)alloc((size_t)n * HID * 2);        // h1 / h2 fp16
  if (o > ws_size) return;

  const int nb2 = (NE + 255) / 256;  // offset-scan blocks
  const int gblocks = n / 16;        // 6250 gemm blocks
  const int fcblocks = (n + 63) / 64;

  // zero row n of g (padding target); rows < n are rewritten every layer
  hipMemsetAsync(B0h + (size_t)n * HID, 0, HID * 2, stream);

  // ---- graph preprocessing (deterministic counting sort; no global atomics)
  count_chunks<<<NBLK, 256, 0, stream>>>(dst, cnt2, E, nbk);
  scan_blocks<<<nb2, 256, 0, stream>>>(cnt2, off, bsum2, NE);
  scan_top<<<1, 512, 0, stream>>>(bsum2, nb2);
  add_offsets2<<<nb2, 256, 0, stream>>>(off, bsum2, boff, NE, E, nbk);
  fill_pairs<<<NBLK, 512, 0, stream>>>(src, dst, off, pairs, E, nbk);
  bucket_csr<<<nbk, 1024, 0, stream>>>(pairs, boff, rowptr, rowend, dinv,
                                       colidx, n, nbk);

  const int pull_blocks = (n * 64 + 255) / 256;  // one wave per node

  // ---- layer 1
  gemm_nodes<128><<<gblocks, 256, 0, stream>>>(x, W1, dinv, B0h);
  gather_agg<<<pull_blocks, 256, 0, stream>>>(rowptr, rowend, colidx,
      (const __half2*)B0h, dinv, b1, (__half2*)B1h, n);

  // ---- layer 2
  gemm_nodes_h<<<gblocks, 256, 0, stream>>>(B1h, W2, dinv, B0h);
  gather_agg<<<pull_blocks, 256, 0, stream>>>(rowptr, rowend, colidx,
      (const __half2*)B0h, dinv, b2, (__half2*)B1h, n);

  // ---- FC head (fp16 activations in, 64 rows/block)
  gemm_fc<<<fcblocks, 256, 0, stream>>>(B1h, Wfc, bfc, out, n);
}

// Round 21
// 251.100 us; speedup vs baseline: 1.0817x; 1.0008x over previous
//
#include <hip/hip_runtime.h>
#include <hip/hip_fp16.h>

#define HID 64
#define SH 9          // log2(nodes per bucket)
#define BKN 512       // nodes per bucket
#define MAXB1 256     // max buckets supported (n <= 131072)
#define NBLK 512      // edge-chunk blocks for the counting sort
typedef unsigned int u32;

// ---------------------------------------------------------------- per-(block,bucket) histogram
__global__ __launch_bounds__(256) void count_chunks(const int* __restrict__ dst,
                                                    int* __restrict__ cnt2,
                                                    int E, int nbk) {
  __shared__ int lc[MAXB1];
  const int t = threadIdx.x;
  for (int b = t; b < nbk; b += 256) lc[b] = 0;
  __syncthreads();
  const int C = (E + NBLK - 1) / NBLK;
  const int s0 = blockIdx.x * C;
  const int s1 = min(s0 + C, E);
  for (int i = s0 + t; i < s1; i += 256) atomicAdd(&lc[dst[i] >> SH], 1);
  __syncthreads();
  for (int b = t; b < nbk; b += 256)
    cnt2[(size_t)b * NBLK + blockIdx.x] = lc[b];  // bucket-major for the scan
}

// ---------------------------------------------------------------- hierarchical scan (cnt2)
__global__ __launch_bounds__(256) void scan_blocks(const int* __restrict__ v_in,
                                                   int* __restrict__ excl,
                                                   int* __restrict__ bsum, int n) {
  __shared__ int s[256];
  const int t = threadIdx.x;
  const int i = blockIdx.x * 256 + t;
  const int v = (i < n) ? v_in[i] : 0;
  s[t] = v;
  __syncthreads();
  for (int off = 1; off < 256; off <<= 1) {
    const int u = (t >= off) ? s[t - off] : 0;
    __syncthreads();
    s[t] += u;
    __syncthreads();
  }
  if (i < n) excl[i] = s[t] - v;
  if (t == 255) bsum[blockIdx.x] = s[255];
}

__global__ __launch_bounds__(512) void scan_top(int* bsum, int nb) {
  __shared__ int s[512];
  const int t = threadIdx.x;
  const int v = (t < nb) ? bsum[t] : 0;
  s[t] = v;
  __syncthreads();
  for (int off = 1; off < 512; off <<= 1) {
    const int u = (t >= off) ? s[t - off] : 0;
    __syncthreads();
    s[t] += u;
    __syncthreads();
  }
  if (t < nb) bsum[t] = s[t] - v;
}

__global__ __launch_bounds__(256) void add_offsets2(int* __restrict__ off,
                                                    const int* __restrict__ bsum,
                                                    int* __restrict__ boff,
                                                    int NE, int E, int nbk) {
  const int m = blockIdx.x * 256 + threadIdx.x;
  if (m < NE) {
    const int v = off[m] + bsum[blockIdx.x];
    off[m] = v;
    if ((m & (NBLK - 1)) == 0) boff[m >> 9] = v;  // NBLK = 512
  }
  if (m == 0) boff[nbk] = E;
}

// ---------------------------------------------------------------- fill pairs (deterministic)
// packed u32: (dstLocal<<17) | src
__global__ __launch_bounds__(512) void fill_pairs(const int* __restrict__ src,
                                                  const int* __restrict__ dst,
                                                  const int* __restrict__ off,
                                                  u32* __restrict__ pairs,
                                                  int E, int nbk) {
  __shared__ int lbase[MAXB1];
  __shared__ int lrank[MAXB1];
  const int t = threadIdx.x;
  for (int b = t; b < nbk; b += 512) {
    lbase[b] = off[(size_t)b * NBLK + blockIdx.x];
    lrank[b] = 0;
  }
  __syncthreads();
  const int C = (E + NBLK - 1) / NBLK;
  const int s0 = blockIdx.x * C;
  const int s1 = min(s0 + C, E);
  for (int i = s0 + t; i < s1; i += 512) {
    const int d = dst[i];
    const int b = d >> SH;
    const int r = atomicAdd(&lrank[b], 1);
    pairs[lbase[b] + r] = ((u32)(d & (BKN - 1)) << 17) | (u32)src[i];
  }
}

// ---------------------------------------------------------------- fused CSR build (padded rows)
// Rows padded to multiples of 8: [self-loop][dg real edges][dummies -> zero-row n].
// Per-bucket padded base = boff[bkt] + bkt*BKN*8 (slack bound: +8/node max).
__global__ __launch_bounds__(1024) void bucket_csr(const u32* __restrict__ pairs,
                                                   const int* __restrict__ boff,
                                                   int* __restrict__ rowptr,
                                                   int* __restrict__ rowend,
                                                   float* __restrict__ dinv,
                                                   int* __restrict__ colidx,
                                                   int n, int nbk) {
  __shared__ int ldeg[BKN];
  __shared__ int lofs[BKN];
  const int bkt = blockIdx.x;
  const int t = threadIdx.x;
  if (t < BKN) ldeg[t] = 0;
  __syncthreads();
  const int beg = boff[bkt], end = boff[bkt + 1];
  const int cnt = end - beg;
  for (int e = t; e < cnt; e += 1024)
    atomicAdd(&ldeg[pairs[beg + e] >> 17], 1);
  __syncthreads();
  const int node = bkt * BKN + t;
  int dg = 0, pdg = 0;
  if (t < BKN) {
    dg = ldeg[t];
    pdg = (node < n) ? ((dg + 1 + 7) & ~7) : 0;  // +1 self-loop, pad to 8
    lofs[t] = pdg;
  }
  __syncthreads();
  for (int o = 1; o < BKN; o <<= 1) {  // Hillis-Steele inclusive scan (512 wide)
    int u = 0;
    if (t < BKN && t >= o) u = lofs[t - o];
    __syncthreads();
    if (t < BKN) lofs[t] += u;
    __syncthreads();
  }
  const int pbase = beg + bkt * (BKN * 8);  // padded bucket base
  if (t < BKN && node < n) {
    const int base = pbase + lofs[t] - pdg;  // exclusive
    rowptr[node] = base;
    rowend[node] = base + pdg;
    dinv[node] = rsqrtf((float)(dg + 1));
    colidx[base] = node;                              // self-loop as edge 0
    for (int j = 1 + dg; j < pdg; ++j) colidx[base + j] = n;  // zero-row pads
    ldeg[t] = base + 1;  // cursor after self-loop
  }
  __syncthreads();
  for (int e = t; e < cnt; e += 1024) {
    const u32 p = pairs[beg + e];  // L2-hot re-read
    const int pos = atomicAdd(&ldeg[p >> 17], 1);
    colidx[pos] = (int)(p & 0x1FFFF);
  }
}

// ---------------------------------------------------------------- dense transform (fp32 in)
// g[i, c] = fp16( dinv[i] * sum_k x[i,k] * W[k,c] )
template <int K>
__global__ __launch_bounds__(256) void gemm_nodes(const float* __restrict__ x,
                                                  const float* __restrict__ W,
                                                  const float* __restrict__ dinv,
                                                  __half* __restrict__ out) {
  __shared__ float Wl[K * 64];
  __shared__ float xl[16][K + 4];
  const int tid = threadIdx.x;
  for (int i = tid; i < K * 16; i += 256)
    reinterpret_cast<float4*>(Wl)[i] = reinterpret_cast<const float4*>(W)[i];
  const int row0 = blockIdx.x * 16;
  for (int i = tid; i < 16 * (K / 4); i += 256) {
    const int r = i / (K / 4), q = i % (K / 4);
    reinterpret_cast<float4*>(&xl[r][0])[q] =
        reinterpret_cast<const float4*>(x + (size_t)(row0 + r) * K)[q];
  }
  __syncthreads();
  const int r = tid >> 4;
  const int cg = (tid & 15) << 2;
  float4 acc = {0.f, 0.f, 0.f, 0.f};
#pragma unroll
  for (int k = 0; k < K; k += 4) {
    const float4 xv = *reinterpret_cast<const float4*>(&xl[r][k]);
    const float4 w0 = *reinterpret_cast<const float4*>(&Wl[(k + 0) * 64 + cg]);
    const float4 w1 = *reinterpret_cast<const float4*>(&Wl[(k + 1) * 64 + cg]);
    const float4 w2 = *reinterpret_cast<const float4*>(&Wl[(k + 2) * 64 + cg]);
    const float4 w3 = *reinterpret_cast<const float4*>(&Wl[(k + 3) * 64 + cg]);
    acc.x = fmaf(xv.w, w3.x, fmaf(xv.z, w2.x, fmaf(xv.y, w1.x, fmaf(xv.x, w0.x, acc.x))));
    acc.y = fmaf(xv.w, w3.y, fmaf(xv.z, w2.y, fmaf(xv.y, w1.y, fmaf(xv.x, w0.y, acc.y))));
    acc.z = fmaf(xv.w, w3.z, fmaf(xv.z, w2.z, fmaf(xv.y, w1.z, fmaf(xv.x, w0.z, acc.z))));
    acc.w = fmaf(xv.w, w3.w, fmaf(xv.z, w2.w, fmaf(xv.y, w1.w, fmaf(xv.x, w0.w, acc.w))));
  }
  const int grow = row0 + r;
  const float di = dinv[grow];
  __half2* op = reinterpret_cast<__half2*>(out + (size_t)grow * 64 + cg);
  op[0] = __floats2half2_rn(acc.x * di, acc.y * di);
  op[1] = __floats2half2_rn(acc.z * di, acc.w * di);
}

// ---------------------------------------------------------------- dense transform (fp16 in, K=64)
__global__ __launch_bounds__(256) void gemm_nodes_h(const __half* __restrict__ x,
                                                    const float* __restrict__ W,
                                                    const float* __restrict__ dinv,
                                                    __half* __restrict__ out) {
  __shared__ float Wl[64 * 64];
  __shared__ float xl[16][68];
  const int tid = threadIdx.x;
  for (int i = tid; i < 64 * 16; i += 256)
    reinterpret_cast<float4*>(Wl)[i] = reinterpret_cast<const float4*>(W)[i];
  const int row0 = blockIdx.x * 16;
  if (tid < 128) {  // 16 rows x 8 chunks of 8 fp16 (16B loads)
    const int r = tid >> 3, q = tid & 7;
    const float4 hv = *reinterpret_cast<const float4*>(
        x + (size_t)(row0 + r) * 64 + q * 8);
    const __half2* hp = reinterpret_cast<const __half2*>(&hv);
#pragma unroll
    for (int j = 0; j < 4; ++j) {
      const float2 f = __half22float2(hp[j]);
      xl[r][q * 8 + 2 * j + 0] = f.x;
      xl[r][q * 8 + 2 * j + 1] = f.y;
    }
  }
  __syncthreads();
  const int r = tid >> 4;
  const int cg = (tid & 15) << 2;
  float4 acc = {0.f, 0.f, 0.f, 0.f};
#pragma unroll
  for (int k = 0; k < 64; k += 4) {
    const float4 xv = *reinterpret_cast<const float4*>(&xl[r][k]);
    const float4 w0 = *reinterpret_cast<const float4*>(&Wl[(k + 0) * 64 + cg]);
    const float4 w1 = *reinterpret_cast<const float4*>(&Wl[(k + 1) * 64 + cg]);
    const float4 w2 = *reinterpret_cast<const float4*>(&Wl[(k + 2) * 64 + cg]);
    const float4 w3 = *reinterpret_cast<const float4*>(&Wl[(k + 3) * 64 + cg]);
    acc.x = fmaf(xv.w, w3.x, fmaf(xv.z, w2.x, fmaf(xv.y, w1.x, fmaf(xv.x, w0.x, acc.x))));
    acc.y = fmaf(xv.w, w3.y, fmaf(xv.z, w2.y, fmaf(xv.y, w1.y, fmaf(xv.x, w0.y, acc.y))));
    acc.z = fmaf(xv.w, w3.z, fmaf(xv.z, w2.z, fmaf(xv.y, w1.z, fmaf(xv.x, w0.z, acc.z))));
    acc.w = fmaf(xv.w, w3.w, fmaf(xv.z, w2.w, fmaf(xv.y, w1.w, fmaf(xv.x, w0.w, acc.w))));
  }
  const int grow = row0 + r;
  const float di = dinv[grow];
  __half2* op = reinterpret_cast<__half2*>(out + (size_t)grow * 64 + cg);
  op[0] = __floats2half2_rn(acc.x * di, acc.y * di);
  op[1] = __floats2half2_rn(acc.z * di, acc.w * di);
}

// ---------------------------------------------------------------- pull aggregation (padded rows)
// rows are multiples of 8 edges incl. self-loop + zero-row pads: no ragged
// tail, minimum 4 loads in flight at all times.
__global__ __launch_bounds__(256) void gather_agg(const int* __restrict__ rowptr,
                                                  const int* __restrict__ rowend,
                                                  const int* __restrict__ colidx,
                                                  const __half2* __restrict__ g2,
                                                  const float* __restrict__ dinv,
                                                  const float* __restrict__ bias,
                                                  __half2* __restrict__ outp, int n) {
  const int lane = threadIdx.x & 63;
  const int node = (blockIdx.x * 256 + threadIdx.x) >> 6;
  if (node >= n) return;
  const int h = lane >> 5;
  const int l = lane & 31;
  const int beg = rowptr[node];
  const int end = rowend[node];
  float2 acc = {0.f, 0.f};
  int e = beg + h;
  for (; e + 30 < end; e += 32) {  // 32 edges/wave-iter, 16 loads/half in flight
    int s[16];
#pragma unroll
    for (int j = 0; j < 16; ++j) s[j] = colidx[e + 2 * j];
    float2 v[16];
#pragma unroll
    for (int j = 0; j < 16; ++j)
      v[j] = __half22float2(g2[((u32)s[j] << 5) + (u32)l]);
#pragma unroll
    for (int j = 0; j < 16; ++j) {
      acc.x += v[j].x;
      acc.y += v[j].y;
    }
  }
  for (; e + 6 < end; e += 8) {  // 8-edge granularity; exact (rows % 8 == 0)
    const int s0 = colidx[e + 0], s1 = colidx[e + 2];
    const int s2 = colidx[e + 4], s3 = colidx[e + 6];
    const float2 v0 = __half22float2(g2[((u32)s0 << 5) + (u32)l]);
    const float2 v1 = __half22float2(g2[((u32)s1 << 5) + (u32)l]);
    const float2 v2 = __half22float2(g2[((u32)s2 << 5) + (u32)l]);
    const float2 v3 = __half22float2(g2[((u32)s3 << 5) + (u32)l]);
    acc.x += (v0.x + v1.x) + (v2.x + v3.x);
    acc.y += (v0.y + v1.y) + (v2.y + v3.y);
  }
  acc.x += __shfl_xor(acc.x, 32);
  acc.y += __shfl_xor(acc.y, 32);
  const float di = dinv[node];
  const float2 bb = reinterpret_cast<const float2*>(bias)[l];
  const float rx = fmaxf(fmaf(acc.x, di, bb.x), 0.f);
  const float ry = fmaxf(fmaf(acc.y, di, bb.y), 0.f);
  if (h == 0) outp[(size_t)node * 32 + l] = __floats2half2_rn(rx, ry);
}

// ---------------------------------------------------------------- final FC (64 -> 11, fp16 in)
// 64 rows/block: W-stage amortized over 4 row-groups
__global__ __launch_bounds__(256) void gemm_fc(const __half* __restrict__ h,
                                               const float* __restrict__ W,
                                               const float* __restrict__ b,
                                               float* __restrict__ out, int n) {
  __shared__ float Wl[772];
  __shared__ float xl[16][68];
  const int tid = threadIdx.x;
  for (int i = tid; i < 772; i += 256) Wl[i] = 0.f;
  __syncthreads();
  for (int i = tid; i < 64 * 11; i += 256) Wl[(i / 11) * 12 + (i % 11)] = W[i];
  const int row00 = blockIdx.x * 64;
  for (int rr = 0; rr < 4; ++rr) {
    const int row0 = row00 + rr * 16;
    __syncthreads();  // covers Wl fill (rr=0) and xl reuse (rr>0)
    if (tid < 128) {  // 16 rows x 8 chunks of 8 fp16
      const int r = tid >> 3, q = tid & 7;
      const int grow = row0 + r;
      if (grow < n) {
        const float4 hv = *reinterpret_cast<const float4*>(
            h + (size_t)grow * 64 + q * 8);
        const __half2* hp = reinterpret_cast<const __half2*>(&hv);
#pragma unroll
        for (int j = 0; j < 4; ++j) {
          const float2 f = __half22float2(hp[j]);
          xl[r][q * 8 + 2 * j + 0] = f.x;
          xl[r][q * 8 + 2 * j + 1] = f.y;
        }
      }
    }
    __syncthreads();
    const int r = tid >> 4, c = tid & 15;
    float acc = 0.f;
#pragma unroll
    for (int k = 0; k < 64; k += 4) {
      acc = fmaf(xl[r][k + 0], Wl[(k + 0) * 12 + c], acc);
      acc = fmaf(xl[r][k + 1], Wl[(k + 1) * 12 + c], acc);
      acc = fmaf(xl[r][k + 2], Wl[(k + 2) * 12 + c], acc);
      acc = fmaf(xl[r][k + 3], Wl[(k + 3) * 12 + c], acc);
    }
    const int grow = row0 + r;
    if (c < 11 && grow < n) out[(size_t)grow * 11 + c] = acc + b[c];
  }
}

// ---------------------------------------------------------------- launch
extern "C" void kernel_launch(void* const* d_in, const int* in_sizes, int n_in,
                              void* d_out, int out_size, void* d_ws, size_t ws_size,
                              hipStream_t stream) {
  const float* x   = (const float*)d_in[0];
  const int*   ei  = (const int*)d_in[1];   // [2, E] int32
  const float* W1  = (const float*)d_in[2];
  const float* b1  = (const float*)d_in[3];
  const float* W2  = (const float*)d_in[4];
  const float* b2  = (const float*)d_in[5];
  const float* Wfc = (const float*)d_in[6];
  const float* bfc = (const float*)d_in[7];
  float* out = (float*)d_out;

  const int n = in_sizes[0] / 128;  // 100000
  const int E = in_sizes[1] / 2;    // 3200000
  const int* src = ei;
  const int* dst = ei + E;
  const int nbk = (n + BKN - 1) >> SH;  // 196 buckets
  const int NE = nbk * NBLK;            // 100352 count entries

  char* ws = (char*)d_ws;
  size_t o = 0;
  auto alloc = [&](size_t bytes) {
    char* p = ws + o;
    o += (bytes + 255) & ~(size_t)255;
    return p;
  };
  float*  dinv   = (float*) alloc((size_t)n * 4);
  int*    rowptr = (int*)   alloc((size_t)n * 4);
  int*    rowend = (int*)   alloc((size_t)n * 4);
  int*    cnt2   = (int*)   alloc((size_t)NE * 4);
  int*    off    = (int*)   alloc((size_t)NE * 4);
  int*    bsum2  = (int*)   alloc(512 * 4);
  int*    boff   = (int*)   alloc((size_t)(nbk + 1) * 4);
  u32*    pairs  = (u32*)   alloc((size_t)E * 4);
  int*    colidx = (int*)   alloc(((size_t)E + (size_t)nbk * BKN * 8) * 4);
  __half* B0h    = (__half*)alloc((size_t)(n + 1) * HID * 2);  // g fp16 (+zero row)
  __half* B1h    = (__half*)alloc((size_t)n * HID * 2);        // h1 / h2 fp16
  if (o > ws_size) return;

  const int nb2 = (NE + 255) / 256;  // offset-scan blocks
  const int gblocks = n / 16;        // 6250 gemm blocks
  const int fcblocks = (n + 63) / 64;

  // zero row n of g (padding target); rows < n are rewritten every layer
  hipMemsetAsync(B0h + (size_t)n * HID, 0, HID * 2, stream);

  // ---- graph preprocessing (deterministic counting sort; no global atomics)
  count_chunks<<<NBLK, 256, 0, stream>>>(dst, cnt2, E, nbk);
  scan_blocks<<<nb2, 256, 0, stream>>>(cnt2, off, bsum2, NE);
  scan_top<<<1, 512, 0, stream>>>(bsum2, nb2);
  add_offsets2<<<nb2, 256, 0, stream>>>(off, bsum2, boff, NE, E, nbk);
  fill_pairs<<<NBLK, 512, 0, stream>>>(src, dst, off, pairs, E, nbk);
  bucket_csr<<<nbk, 1024, 0, stream>>>(pairs, boff, rowptr, rowend, dinv,
                                       colidx, n, nbk);

  const int pull_blocks = (n * 64 + 255) / 256;  // one wave per node

  // ---- layer 1
  gemm_nodes<128><<<gblocks, 256, 0, stream>>>(x, W1, dinv, B0h);
  gather_agg<<<pull_blocks, 256, 0, stream>>>(rowptr, rowend, colidx,
      (const __half2*)B0h, dinv, b1, (__half2*)B1h, n);

  // ---- layer 2
  gemm_nodes_h<<<gblocks, 256, 0, stream>>>(B1h, W2, dinv, B0h);
  gather_agg<<<pull_blocks, 256, 0, stream>>>(rowptr, rowend, colidx,
      (const __half2*)B0h, dinv, b2, (__half2*)B1h, n);

  // ---- FC head (fp16 activations in, 64 rows/block)
  gemm_fc<<<fcblocks, 256, 0, stream>>>(B1h, Wfc, bfc, out, n);
}

// Round 22
// 219.336 us; speedup vs baseline: 1.2384x; 1.1448x over previous
//
#include <hip/hip_runtime.h>
#include <hip/hip_fp16.h>

#define HID 64
#define SH 9          // log2(nodes per bucket)
#define BKN 512       // nodes per bucket
#define MAXB1 256     // max buckets supported (n <= 131072)
#define NBLK 512      // edge-chunk blocks for the counting sort
typedef unsigned int u32;
typedef float f32x4 __attribute__((ext_vector_type(4)));
typedef _Float16 f16x4 __attribute__((ext_vector_type(4)));
typedef _Float16 f16x8 __attribute__((ext_vector_type(8)));

// ---------------------------------------------------------------- per-(block,bucket) histogram
__global__ __launch_bounds__(256) void count_chunks(const int* __restrict__ dst,
                                                    int* __restrict__ cnt2,
                                                    int E, int nbk) {
  __shared__ int lc[MAXB1];
  const int t = threadIdx.x;
  for (int b = t; b < nbk; b += 256) lc[b] = 0;
  __syncthreads();
  const int C = (E + NBLK - 1) / NBLK;
  const int s0 = blockIdx.x * C;
  const int s1 = min(s0 + C, E);
  for (int i = s0 + t; i < s1; i += 256) atomicAdd(&lc[dst[i] >> SH], 1);
  __syncthreads();
  for (int b = t; b < nbk; b += 256)
    cnt2[(size_t)b * NBLK + blockIdx.x] = lc[b];  // bucket-major for the scan
}

// ---------------------------------------------------------------- hierarchical scan (cnt2)
__global__ __launch_bounds__(256) void scan_blocks(const int* __restrict__ v_in,
                                                   int* __restrict__ excl,
                                                   int* __restrict__ bsum, int n) {
  __shared__ int s[256];
  const int t = threadIdx.x;
  const int i = blockIdx.x * 256 + t;
  const int v = (i < n) ? v_in[i] : 0;
  s[t] = v;
  __syncthreads();
  for (int off = 1; off < 256; off <<= 1) {
    const int u = (t >= off) ? s[t - off] : 0;
    __syncthreads();
    s[t] += u;
    __syncthreads();
  }
  if (i < n) excl[i] = s[t] - v;
  if (t == 255) bsum[blockIdx.x] = s[255];
}

__global__ __launch_bounds__(512) void scan_top(int* bsum, int nb) {
  __shared__ int s[512];
  const int t = threadIdx.x;
  const int v = (t < nb) ? bsum[t] : 0;
  s[t] = v;
  __syncthreads();
  for (int off = 1; off < 512; off <<= 1) {
    const int u = (t >= off) ? s[t - off] : 0;
    __syncthreads();
    s[t] += u;
    __syncthreads();
  }
  if (t < nb) bsum[t] = s[t] - v;
}

__global__ __launch_bounds__(256) void add_offsets2(int* __restrict__ off,
                                                    const int* __restrict__ bsum,
                                                    int* __restrict__ boff,
                                                    int NE, int E, int nbk) {
  const int m = blockIdx.x * 256 + threadIdx.x;
  if (m < NE) {
    const int v = off[m] + bsum[blockIdx.x];
    off[m] = v;
    if ((m & (NBLK - 1)) == 0) boff[m >> 9] = v;  // NBLK = 512
  }
  if (m == 0) boff[nbk] = E;
}

// ---------------------------------------------------------------- fill pairs (deterministic)
// packed u32: (dstLocal<<17) | src
__global__ __launch_bounds__(512) void fill_pairs(const int* __restrict__ src,
                                                  const int* __restrict__ dst,
                                                  const int* __restrict__ off,
                                                  u32* __restrict__ pairs,
                                                  int E, int nbk) {
  __shared__ int lbase[MAXB1];
  __shared__ int lrank[MAXB1];
  const int t = threadIdx.x;
  for (int b = t; b < nbk; b += 512) {
    lbase[b] = off[(size_t)b * NBLK + blockIdx.x];
    lrank[b] = 0;
  }
  __syncthreads();
  const int C = (E + NBLK - 1) / NBLK;
  const int s0 = blockIdx.x * C;
  const int s1 = min(s0 + C, E);
  for (int i = s0 + t; i < s1; i += 512) {
    const int d = dst[i];
    const int b = d >> SH;
    const int r = atomicAdd(&lrank[b], 1);
    pairs[lbase[b] + r] = ((u32)(d & (BKN - 1)) << 17) | (u32)src[i];
  }
}

// ---------------------------------------------------------------- fused CSR build (padded rows)
// Rows padded to multiples of 8: [self-loop][dg real edges][dummies -> zero-row n].
__global__ __launch_bounds__(1024) void bucket_csr(const u32* __restrict__ pairs,
                                                   const int* __restrict__ boff,
                                                   int* __restrict__ rowptr,
                                                   int* __restrict__ rowend,
                                                   float* __restrict__ dinv,
                                                   int* __restrict__ colidx,
                                                   int n, int nbk) {
  __shared__ int ldeg[BKN];
  __shared__ int lofs[BKN];
  const int bkt = blockIdx.x;
  const int t = threadIdx.x;
  if (t < BKN) ldeg[t] = 0;
  __syncthreads();
  const int beg = boff[bkt], end = boff[bkt + 1];
  const int cnt = end - beg;
  for (int e = t; e < cnt; e += 1024)
    atomicAdd(&ldeg[pairs[beg + e] >> 17], 1);
  __syncthreads();
  const int node = bkt * BKN + t;
  int dg = 0, pdg = 0;
  if (t < BKN) {
    dg = ldeg[t];
    pdg = (node < n) ? ((dg + 1 + 7) & ~7) : 0;  // +1 self-loop, pad to 8
    lofs[t] = pdg;
  }
  __syncthreads();
  for (int o = 1; o < BKN; o <<= 1) {  // Hillis-Steele inclusive scan (512 wide)
    int u = 0;
    if (t < BKN && t >= o) u = lofs[t - o];
    __syncthreads();
    if (t < BKN) lofs[t] += u;
    __syncthreads();
  }
  const int pbase = beg + bkt * (BKN * 8);  // padded bucket base
  if (t < BKN && node < n) {
    const int base = pbase + lofs[t] - pdg;  // exclusive
    rowptr[node] = base;
    rowend[node] = base + pdg;
    dinv[node] = rsqrtf((float)(dg + 1));
    colidx[base] = node;                              // self-loop as edge 0
    for (int j = 1 + dg; j < pdg; ++j) colidx[base + j] = n;  // zero-row pads
    ldeg[t] = base + 1;  // cursor after self-loop
  }
  __syncthreads();
  for (int e = t; e < cnt; e += 1024) {
    const u32 p = pairs[beg + e];  // L2-hot re-read
    const int pos = atomicAdd(&ldeg[p >> 17], 1);
    colidx[pos] = (int)(p & 0x1FFFF);
  }
}

// ---------------------------------------------------------------- MFMA gemm, layer 1 (fp32 x, K=128)
// g[i,c] = fp16(dinv[i] * sum_k x[i,k] * W[k,c]); 64-row blocks, 4 waves,
// each wave: 16 rows x 64 cols via 4 n-tiles of mfma_f32_16x16x32_f16.
__global__ __launch_bounds__(256) void gemm1_mfma(const float* __restrict__ x,
                                                  const float* __restrict__ W,
                                                  const float* __restrict__ dinv,
                                                  __half* __restrict__ out, int n) {
  __shared__ _Float16 Ah[64 * 136];  // [row][k], stride 136 (pad 8 -> 2-way banks)
  __shared__ _Float16 Wt[64 * 136];  // [col][k] transposed
  const int tid = threadIdx.x;
  const int row0 = blockIdx.x * 64;
  // stage x -> Ah fp16 (coalesced float4 reads)
  for (int i = tid; i < 64 * 32; i += 256) {
    const int r = i >> 5, q = i & 31;
    const int gr = row0 + r;
    float4 v = {0.f, 0.f, 0.f, 0.f};
    if (gr < n) v = reinterpret_cast<const float4*>(x)[(size_t)gr * 32 + q];
    f16x4 hv = {(_Float16)v.x, (_Float16)v.y, (_Float16)v.z, (_Float16)v.w};
    *reinterpret_cast<f16x4*>(&Ah[r * 136 + q * 4]) = hv;
  }
  // stage W -> Wt transposed fp16 (per k-quad, lanes sweep cols: coalesced)
  for (int i = tid; i < 64 * 32; i += 256) {
    const int c = i & 63, k0 = (i >> 6) * 4;
    f16x4 hv = {(_Float16)W[(size_t)(k0 + 0) * 64 + c],
                (_Float16)W[(size_t)(k0 + 1) * 64 + c],
                (_Float16)W[(size_t)(k0 + 2) * 64 + c],
                (_Float16)W[(size_t)(k0 + 3) * 64 + c]};
    *reinterpret_cast<f16x4*>(&Wt[c * 136 + k0]) = hv;
  }
  __syncthreads();
  const int lane = tid & 63;
  const int m = lane & 15, g = lane >> 4;
  const int r0 = (tid >> 6) * 16;  // wave's row stripe
  f32x4 acc0 = {0.f, 0.f, 0.f, 0.f}, acc1 = acc0, acc2 = acc0, acc3 = acc0;
  const _Float16* arow = &Ah[(r0 + m) * 136];
#pragma unroll
  for (int kc = 0; kc < 4; ++kc) {
    const int ko = kc * 32 + g * 4;
    const f16x4 alo = *reinterpret_cast<const f16x4*>(arow + ko);
    const f16x4 ahi = *reinterpret_cast<const f16x4*>(arow + ko + 16);
    const f16x8 a = __builtin_shufflevector(alo, ahi, 0, 1, 2, 3, 4, 5, 6, 7);
    const f16x4 bl0 = *reinterpret_cast<const f16x4*>(&Wt[(0  + m) * 136 + ko]);
    const f16x4 bh0 = *reinterpret_cast<const f16x4*>(&Wt[(0  + m) * 136 + ko + 16]);
    const f16x4 bl1 = *reinterpret_cast<const f16x4*>(&Wt[(16 + m) * 136 + ko]);
    const f16x4 bh1 = *reinterpret_cast<const f16x4*>(&Wt[(16 + m) * 136 + ko + 16]);
    const f16x4 bl2 = *reinterpret_cast<const f16x4*>(&Wt[(32 + m) * 136 + ko]);
    const f16x4 bh2 = *reinterpret_cast<const f16x4*>(&Wt[(32 + m) * 136 + ko + 16]);
    const f16x4 bl3 = *reinterpret_cast<const f16x4*>(&Wt[(48 + m) * 136 + ko]);
    const f16x4 bh3 = *reinterpret_cast<const f16x4*>(&Wt[(48 + m) * 136 + ko + 16]);
    const f16x8 b0 = __builtin_shufflevector(bl0, bh0, 0, 1, 2, 3, 4, 5, 6, 7);
    const f16x8 b1 = __builtin_shufflevector(bl1, bh1, 0, 1, 2, 3, 4, 5, 6, 7);
    const f16x8 b2 = __builtin_shufflevector(bl2, bh2, 0, 1, 2, 3, 4, 5, 6, 7);
    const f16x8 b3 = __builtin_shufflevector(bl3, bh3, 0, 1, 2, 3, 4, 5, 6, 7);
    acc0 = __builtin_amdgcn_mfma_f32_16x16x32_f16(a, b0, acc0, 0, 0, 0);
    acc1 = __builtin_amdgcn_mfma_f32_16x16x32_f16(a, b1, acc1, 0, 0, 0);
    acc2 = __builtin_amdgcn_mfma_f32_16x16x32_f16(a, b2, acc2, 0, 0, 0);
    acc3 = __builtin_amdgcn_mfma_f32_16x16x32_f16(a, b3, acc3, 0, 0, 0);
  }
  // C/D: row = g*4 + j, col = m (m89-verified, dtype-independent)
  _Float16* o16 = reinterpret_cast<_Float16*>(out);
#pragma unroll
  for (int j = 0; j < 4; ++j) {
    const int grow = row0 + r0 + g * 4 + j;
    if (grow < n) {
      const float di = dinv[grow];
      o16[(size_t)grow * 64 + 0  + m] = (_Float16)(acc0[j] * di);
      o16[(size_t)grow * 64 + 16 + m] = (_Float16)(acc1[j] * di);
      o16[(size_t)grow * 64 + 32 + m] = (_Float16)(acc2[j] * di);
      o16[(size_t)grow * 64 + 48 + m] = (_Float16)(acc3[j] * di);
    }
  }
}

// ---------------------------------------------------------------- MFMA gemm, layer 2 (fp16 h, K=64)
__global__ __launch_bounds__(256) void gemm2_mfma(const __half* __restrict__ h,
                                                  const float* __restrict__ W,
                                                  const float* __restrict__ dinv,
                                                  __half* __restrict__ out, int n) {
  __shared__ _Float16 Ah[64 * 72];  // stride 72 (pad 8)
  __shared__ _Float16 Wt[64 * 72];
  const int tid = threadIdx.x;
  const int row0 = blockIdx.x * 64;
  for (int i = tid; i < 64 * 8; i += 256) {  // 8 halves (16B) per iter
    const int r = i >> 3, q = i & 7;
    const int gr = row0 + r;
    float4 raw = {0.f, 0.f, 0.f, 0.f};
    if (gr < n) raw = reinterpret_cast<const float4*>(h)[(size_t)gr * 8 + q];
    *reinterpret_cast<float4*>(&Ah[r * 72 + q * 8]) = raw;
  }
  for (int i = tid; i < 64 * 16; i += 256) {  // 16 k-quads x 64 cols
    const int c = i & 63, k0 = (i >> 6) * 4;
    f16x4 hv = {(_Float16)W[(size_t)(k0 + 0) * 64 + c],
                (_Float16)W[(size_t)(k0 + 1) * 64 + c],
                (_Float16)W[(size_t)(k0 + 2) * 64 + c],
                (_Float16)W[(size_t)(k0 + 3) * 64 + c]};
    *reinterpret_cast<f16x4*>(&Wt[c * 72 + k0]) = hv;
  }
  __syncthreads();
  const int lane = tid & 63;
  const int m = lane & 15, g = lane >> 4;
  const int r0 = (tid >> 6) * 16;
  f32x4 acc0 = {0.f, 0.f, 0.f, 0.f}, acc1 = acc0, acc2 = acc0, acc3 = acc0;
  const _Float16* arow = &Ah[(r0 + m) * 72];
#pragma unroll
  for (int kc = 0; kc < 2; ++kc) {
    const int ko = kc * 32 + g * 4;
    const f16x4 alo = *reinterpret_cast<const f16x4*>(arow + ko);
    const f16x4 ahi = *reinterpret_cast<const f16x4*>(arow + ko + 16);
    const f16x8 a = __builtin_shufflevector(alo, ahi, 0, 1, 2, 3, 4, 5, 6, 7);
    const f16x4 bl0 = *reinterpret_cast<const f16x4*>(&Wt[(0  + m) * 72 + ko]);
    const f16x4 bh0 = *reinterpret_cast<const f16x4*>(&Wt[(0  + m) * 72 + ko + 16]);
    const f16x4 bl1 = *reinterpret_cast<const f16x4*>(&Wt[(16 + m) * 72 + ko]);
    const f16x4 bh1 = *reinterpret_cast<const f16x4*>(&Wt[(16 + m) * 72 + ko + 16]);
    const f16x4 bl2 = *reinterpret_cast<const f16x4*>(&Wt[(32 + m) * 72 + ko]);
    const f16x4 bh2 = *reinterpret_cast<const f16x4*>(&Wt[(32 + m) * 72 + ko + 16]);
    const f16x4 bl3 = *reinterpret_cast<const f16x4*>(&Wt[(48 + m) * 72 + ko]);
    const f16x4 bh3 = *reinterpret_cast<const f16x4*>(&Wt[(48 + m) * 72 + ko + 16]);
    const f16x8 b0 = __builtin_shufflevector(bl0, bh0, 0, 1, 2, 3, 4, 5, 6, 7);
    const f16x8 b1 = __builtin_shufflevector(bl1, bh1, 0, 1, 2, 3, 4, 5, 6, 7);
    const f16x8 b2 = __builtin_shufflevector(bl2, bh2, 0, 1, 2, 3, 4, 5, 6, 7);
    const f16x8 b3 = __builtin_shufflevector(bl3, bh3, 0, 1, 2, 3, 4, 5, 6, 7);
    acc0 = __builtin_amdgcn_mfma_f32_16x16x32_f16(a, b0, acc0, 0, 0, 0);
    acc1 = __builtin_amdgcn_mfma_f32_16x16x32_f16(a, b1, acc1, 0, 0, 0);
    acc2 = __builtin_amdgcn_mfma_f32_16x16x32_f16(a, b2, acc2, 0, 0, 0);
    acc3 = __builtin_amdgcn_mfma_f32_16x16x32_f16(a, b3, acc3, 0, 0, 0);
  }
  _Float16* o16 = reinterpret_cast<_Float16*>(out);
#pragma unroll
  for (int j = 0; j < 4; ++j) {
    const int grow = row0 + r0 + g * 4 + j;
    if (grow < n) {
      const float di = dinv[grow];
      o16[(size_t)grow * 64 + 0  + m] = (_Float16)(acc0[j] * di);
      o16[(size_t)grow * 64 + 16 + m] = (_Float16)(acc1[j] * di);
      o16[(size_t)grow * 64 + 32 + m] = (_Float16)(acc2[j] * di);
      o16[(size_t)grow * 64 + 48 + m] = (_Float16)(acc3[j] * di);
    }
  }
}

// ---------------------------------------------------------------- pull aggregation (padded rows)
__global__ __launch_bounds__(256) void gather_agg(const int* __restrict__ rowptr,
                                                  const int* __restrict__ rowend,
                                                  const int* __restrict__ colidx,
                                                  const __half2* __restrict__ g2,
                                                  const float* __restrict__ dinv,
                                                  const float* __restrict__ bias,
                                                  __half2* __restrict__ outp, int n) {
  const int lane = threadIdx.x & 63;
  const int node = (blockIdx.x * 256 + threadIdx.x) >> 6;
  if (node >= n) return;
  const int h = lane >> 5;
  const int l = lane & 31;
  const int beg = rowptr[node];
  const int end = rowend[node];
  float2 acc = {0.f, 0.f};
  int e = beg + h;
  for (; e + 30 < end; e += 32) {  // 32 edges/wave-iter, 16 loads/half in flight
    int s[16];
#pragma unroll
    for (int j = 0; j < 16; ++j) s[j] = colidx[e + 2 * j];
    float2 v[16];
#pragma unroll
    for (int j = 0; j < 16; ++j)
      v[j] = __half22float2(g2[((u32)s[j] << 5) + (u32)l]);
#pragma unroll
    for (int j = 0; j < 16; ++j) {
      acc.x += v[j].x;
      acc.y += v[j].y;
    }
  }
  for (; e + 6 < end; e += 8) {  // 8-edge granularity; exact (rows % 8 == 0)
    const int s0 = colidx[e + 0], s1 = colidx[e + 2];
    const int s2 = colidx[e + 4], s3 = colidx[e + 6];
    const float2 v0 = __half22float2(g2[((u32)s0 << 5) + (u32)l]);
    const float2 v1 = __half22float2(g2[((u32)s1 << 5) + (u32)l]);
    const float2 v2 = __half22float2(g2[((u32)s2 << 5) + (u32)l]);
    const float2 v3 = __half22float2(g2[((u32)s3 << 5) + (u32)l]);
    acc.x += (v0.x + v1.x) + (v2.x + v3.x);
    acc.y += (v0.y + v1.y) + (v2.y + v3.y);
  }
  acc.x += __shfl_xor(acc.x, 32);
  acc.y += __shfl_xor(acc.y, 32);
  const float di = dinv[node];
  const float2 bb = reinterpret_cast<const float2*>(bias)[l];
  const float rx = fmaxf(fmaf(acc.x, di, bb.x), 0.f);
  const float ry = fmaxf(fmaf(acc.y, di, bb.y), 0.f);
  if (h == 0) outp[(size_t)node * 32 + l] = __floats2half2_rn(rx, ry);
}

// ---------------------------------------------------------------- final FC (64 -> 11, fp16 in)
__global__ __launch_bounds__(256) void gemm_fc(const __half* __restrict__ h,
                                               const float* __restrict__ W,
                                               const float* __restrict__ b,
                                               float* __restrict__ out, int n) {
  __shared__ float Wl[772];
  __shared__ float xl[16][68];
  const int tid = threadIdx.x;
  for (int i = tid; i < 772; i += 256) Wl[i] = 0.f;
  __syncthreads();
  for (int i = tid; i < 64 * 11; i += 256) Wl[(i / 11) * 12 + (i % 11)] = W[i];
  const int row00 = blockIdx.x * 64;
  for (int rr = 0; rr < 4; ++rr) {
    const int row0 = row00 + rr * 16;
    __syncthreads();  // covers Wl fill (rr=0) and xl reuse (rr>0)
    if (tid < 128) {  // 16 rows x 8 chunks of 8 fp16
      const int r = tid >> 3, q = tid & 7;
      const int grow = row0 + r;
      if (grow < n) {
        const float4 hv = *reinterpret_cast<const float4*>(
            h + (size_t)grow * 64 + q * 8);
        const __half2* hp = reinterpret_cast<const __half2*>(&hv);
#pragma unroll
        for (int j = 0; j < 4; ++j) {
          const float2 f = __half22float2(hp[j]);
          xl[r][q * 8 + 2 * j + 0] = f.x;
          xl[r][q * 8 + 2 * j + 1] = f.y;
        }
      }
    }
    __syncthreads();
    const int r = tid >> 4, c = tid & 15;
    float acc = 0.f;
#pragma unroll
    for (int k = 0; k < 64; k += 4) {
      acc = fmaf(xl[r][k + 0], Wl[(k + 0) * 12 + c], acc);
      acc = fmaf(xl[r][k + 1], Wl[(k + 1) * 12 + c], acc);
      acc = fmaf(xl[r][k + 2], Wl[(k + 2) * 12 + c], acc);
      acc = fmaf(xl[r][k + 3], Wl[(k + 3) * 12 + c], acc);
    }
    const int grow = row0 + r;
    if (c < 11 && grow < n) out[(size_t)grow * 11 + c] = acc + b[c];
  }
}

// ---------------------------------------------------------------- launch
extern "C" void kernel_launch(void* const* d_in, const int* in_sizes, int n_in,
                              void* d_out, int out_size, void* d_ws, size_t ws_size,
                              hipStream_t stream) {
  const float* x   = (const float*)d_in[0];
  const int*   ei  = (const int*)d_in[1];   // [2, E] int32
  const float* W1  = (const float*)d_in[2];
  const float* b1  = (const float*)d_in[3];
  const float* W2  = (const float*)d_in[4];
  const float* b2  = (const float*)d_in[5];
  const float* Wfc = (const float*)d_in[6];
  const float* bfc = (const float*)d_in[7];
  float* out = (float*)d_out;

  const int n = in_sizes[0] / 128;  // 100000
  const int E = in_sizes[1] / 2;    // 3200000
  const int* src = ei;
  const int* dst = ei + E;
  const int nbk = (n + BKN - 1) >> SH;  // 196 buckets
  const int NE = nbk * NBLK;            // 100352 count entries

  char* ws = (char*)d_ws;
  size_t o = 0;
  auto alloc = [&](size_t bytes) {
    char* p = ws + o;
    o += (bytes + 255) & ~(size_t)255;
    return p;
  };
  float*  dinv   = (float*) alloc((size_t)n * 4);
  int*    rowptr = (int*)   alloc((size_t)n * 4);
  int*    rowend = (int*)   alloc((size_t)n * 4);
  int*    cnt2   = (int*)   alloc((size_t)NE * 4);
  int*    off    = (int*)   alloc((size_t)NE * 4);
  int*    bsum2  = (int*)   alloc(512 * 4);
  int*    boff   = (int*)   alloc((size_t)(nbk + 1) * 4);
  u32*    pairs  = (u32*)   alloc((size_t)E * 4);
  int*    colidx = (int*)   alloc(((size_t)E + (size_t)nbk * BKN * 8) * 4);
  __half* B0h    = (__half*)alloc((size_t)(n + 1) * HID * 2);  // g fp16 (+zero row)
  __half* B1h    = (__half*)alloc((size_t)n * HID * 2);        // h1 / h2 fp16
  if (o > ws_size) return;

  const int nb2 = (NE + 255) / 256;     // offset-scan blocks
  const int gblocks = (n + 63) / 64;    // 1563 mfma gemm blocks
  const int fcblocks = (n + 63) / 64;

  // zero row n of g (padding target); rows < n are rewritten every layer
  hipMemsetAsync(B0h + (size_t)n * HID, 0, HID * 2, stream);

  // ---- graph preprocessing (deterministic counting sort; no global atomics)
  count_chunks<<<NBLK, 256, 0, stream>>>(dst, cnt2, E, nbk);
  scan_blocks<<<nb2, 256, 0, stream>>>(cnt2, off, bsum2, NE);
  scan_top<<<1, 512, 0, stream>>>(bsum2, nb2);
  add_offsets2<<<nb2, 256, 0, stream>>>(off, bsum2, boff, NE, E, nbk);
  fill_pairs<<<NBLK, 512, 0, stream>>>(src, dst, off, pairs, E, nbk);
  bucket_csr<<<nbk, 1024, 0, stream>>>(pairs, boff, rowptr, rowend, dinv,
                                       colidx, n, nbk);

  const int pull_blocks = (n * 64 + 255) / 256;  // one wave per node

  // ---- layer 1
  gemm1_mfma<<<gblocks, 256, 0, stream>>>(x, W1, dinv, B0h, n);
  gather_agg<<<pull_blocks, 256, 0, stream>>>(rowptr, rowend, colidx,
      (const __half2*)B0h, dinv, b1, (__half2*)B1h, n);

  // ---- layer 2
  gemm2_mfma<<<gblocks, 256, 0, stream>>>(B1h, W2, dinv, B0h, n);
  gather_agg<<<pull_blocks, 256, 0, stream>>>(rowptr, rowend, colidx,
      (const __half2*)B0h, dinv, b2, (__half2*)B1h, n);

  // ---- FC head (fp16 activations in, 64 rows/block)
  gemm_fc<<<fcblocks, 256, 0, stream>>>(B1h, Wfc, bfc, out, n);
}

// Round 23
// 211.012 us; speedup vs baseline: 1.2872x; 1.0395x over previous
//
#include <hip/hip_runtime.h>
#include <hip/hip_fp16.h>

#define HID 64
#define SH 9          // log2(nodes per bucket)
#define BKN 512       // nodes per bucket
#define MAXB1 256     // max buckets supported (n <= 131072)
#define NBLK 512      // edge-chunk blocks for the counting sort
typedef unsigned int u32;
typedef float f32x4 __attribute__((ext_vector_type(4)));
typedef _Float16 f16x4 __attribute__((ext_vector_type(4)));
typedef _Float16 f16x8 __attribute__((ext_vector_type(8)));

// chunk size, multiple of 4 (shared by count_chunks / fill_pairs)
__device__ __forceinline__ int chunk4(int E) {
  return (((E + NBLK - 1) / NBLK) + 3) & ~3;
}

// ---------------------------------------------------------------- per-(block,bucket) histogram
// deterministic contiguous chunks; int4 edge ingest; LDS-staged counters
__global__ __launch_bounds__(256) void count_chunks(const int* __restrict__ dst,
                                                    int* __restrict__ cnt2,
                                                    int E, int nbk) {
  __shared__ int lc[MAXB1];
  const int t = threadIdx.x;
  for (int b = t; b < nbk; b += 256) lc[b] = 0;
  __syncthreads();
  const int C = chunk4(E);
  const int s0 = blockIdx.x * C;
  const int s1 = min(s0 + C, E);
  for (int i = s0 + t * 4; i < s1; i += 1024) {  // (s1-s0) % 4 == 0, i 4-aligned
    const int4 d4 = *reinterpret_cast<const int4*>(&dst[i]);
    atomicAdd(&lc[d4.x >> SH], 1);
    atomicAdd(&lc[d4.y >> SH], 1);
    atomicAdd(&lc[d4.z >> SH], 1);
    atomicAdd(&lc[d4.w >> SH], 1);
  }
  __syncthreads();
  for (int b = t; b < nbk; b += 256)
    cnt2[(size_t)b * NBLK + blockIdx.x] = lc[b];  // bucket-major for the scan
}

// ---------------------------------------------------------------- hierarchical scan (cnt2)
__global__ __launch_bounds__(256) void scan_blocks(const int* __restrict__ v_in,
                                                   int* __restrict__ excl,
                                                   int* __restrict__ bsum, int n) {
  __shared__ int s[256];
  const int t = threadIdx.x;
  const int i = blockIdx.x * 256 + t;
  const int v = (i < n) ? v_in[i] : 0;
  s[t] = v;
  __syncthreads();
  for (int off = 1; off < 256; off <<= 1) {
    const int u = (t >= off) ? s[t - off] : 0;
    __syncthreads();
    s[t] += u;
    __syncthreads();
  }
  if (i < n) excl[i] = s[t] - v;
  if (t == 255) bsum[blockIdx.x] = s[255];
}

__global__ __launch_bounds__(512) void scan_top(int* bsum, int nb) {
  __shared__ int s[512];
  const int t = threadIdx.x;
  const int v = (t < nb) ? bsum[t] : 0;
  s[t] = v;
  __syncthreads();
  for (int off = 1; off < 512; off <<= 1) {
    const int u = (t >= off) ? s[t - off] : 0;
    __syncthreads();
    s[t] += u;
    __syncthreads();
  }
  if (t < nb) bsum[t] = s[t] - v;
}

// ---------------------------------------------------------------- fill pairs (deterministic)
// packed u32: (dstLocal<<17) | src. Consumes off[] + bsum2[] inline (no
// add_offsets pass). int4 edge ingest.
__global__ __launch_bounds__(512) void fill_pairs(const int* __restrict__ src,
                                                  const int* __restrict__ dst,
                                                  const int* __restrict__ off,
                                                  const int* __restrict__ bsum2,
                                                  u32* __restrict__ pairs,
                                                  int E, int nbk) {
  __shared__ int lbase[MAXB1];
  __shared__ int lrank[MAXB1];
  const int t = threadIdx.x;
  const int blk = blockIdx.x;
  for (int b = t; b < nbk; b += 512) {
    const int m = b * NBLK + blk;
    lbase[b] = off[m] + bsum2[m >> 8];
    lrank[b] = 0;
  }
  __syncthreads();
  const int C = chunk4(E);
  const int s0 = blk * C;
  const int s1 = min(s0 + C, E);
  for (int i = s0 + t * 4; i < s1; i += 2048) {
    const int4 d4 = *reinterpret_cast<const int4*>(&dst[i]);
    const int4 v4 = *reinterpret_cast<const int4*>(&src[i]);
    {
      const int b = d4.x >> SH;
      const int r = atomicAdd(&lrank[b], 1);
      pairs[lbase[b] + r] = ((u32)(d4.x & (BKN - 1)) << 17) | (u32)v4.x;
    }
    {
      const int b = d4.y >> SH;
      const int r = atomicAdd(&lrank[b], 1);
      pairs[lbase[b] + r] = ((u32)(d4.y & (BKN - 1)) << 17) | (u32)v4.y;
    }
    {
      const int b = d4.z >> SH;
      const int r = atomicAdd(&lrank[b], 1);
      pairs[lbase[b] + r] = ((u32)(d4.z & (BKN - 1)) << 17) | (u32)v4.z;
    }
    {
      const int b = d4.w >> SH;
      const int r = atomicAdd(&lrank[b], 1);
      pairs[lbase[b] + r] = ((u32)(d4.w & (BKN - 1)) << 17) | (u32)v4.w;
    }
  }
}

// ---------------------------------------------------------------- fused CSR build (padded rows)
// Rows padded to multiples of 8: [self-loop][dg edges][dummies -> zero-row n].
// Bucket range computed inline from off[]+bsum2[]; wave-shuffle scan (2 barriers).
__global__ __launch_bounds__(1024) void bucket_csr(const u32* __restrict__ pairs,
                                                   const int* __restrict__ off,
                                                   const int* __restrict__ bsum2,
                                                   int* __restrict__ rowptr,
                                                   int* __restrict__ rowend,
                                                   float* __restrict__ dinv,
                                                   int* __restrict__ colidx,
                                                   int n, int nbk, int E) {
  __shared__ int ldeg[BKN];
  __shared__ int wsum[8];
  __shared__ int wexcl[8];
  const int bkt = blockIdx.x;
  const int t = threadIdx.x;
  if (t < BKN) ldeg[t] = 0;
  __syncthreads();
  const int m0 = bkt * NBLK;
  const int beg = off[m0] + bsum2[m0 >> 8];
  const int end = (bkt == nbk - 1)
                      ? E
                      : off[m0 + NBLK] + bsum2[(m0 + NBLK) >> 8];
  const int cnt = end - beg;
  for (int e = t; e < cnt; e += 1024)
    atomicAdd(&ldeg[pairs[beg + e] >> 17], 1);
  __syncthreads();
  const int node = bkt * BKN + t;
  const int lane = t & 63, w = t >> 6;  // waves 0..7 hold the 512 scan entries
  int dg = 0, pdg = 0, incl = 0;
  if (t < BKN) {
    dg = ldeg[t];
    pdg = (node < n) ? ((dg + 8) & ~7) : 0;  // +1 self-loop, pad to 8
    incl = pdg;
  }
#pragma unroll
  for (int o = 1; o < 64; o <<= 1) {  // per-wave inclusive scan
    const int u = __shfl_up(incl, o);
    if (lane >= o) incl += u;
  }
  if (t < BKN && lane == 63) wsum[w] = incl;
  __syncthreads();
  if (t == 0) {
    int run = 0;
#pragma unroll
    for (int i = 0; i < 8; ++i) { wexcl[i] = run; run += wsum[i]; }
  }
  __syncthreads();
  const int pbase = beg + bkt * (BKN * 8);  // padded bucket base
  if (t < BKN && node < n) {
    const int base = pbase + wexcl[w] + incl - pdg;  // exclusive prefix
    rowptr[node] = base;
    rowend[node] = base + pdg;
    dinv[node] = rsqrtf((float)(dg + 1));
    colidx[base] = node;                                      // self-loop
    for (int j = 1 + dg; j < pdg; ++j) colidx[base + j] = n;  // zero-row pads
    ldeg[t] = base + 1;  // cursor after self-loop
  }
  __syncthreads();
  for (int e = t; e < cnt; e += 1024) {
    const u32 p = pairs[beg + e];  // L2-hot re-read
    const int pos = atomicAdd(&ldeg[p >> 17], 1);
    colidx[pos] = (int)(p & 0x1FFFF);
  }
}

// ---------------------------------------------------------------- MFMA gemm, layer 1 (fp32 x, K=128)
__global__ __launch_bounds__(256) void gemm1_mfma(const float* __restrict__ x,
                                                  const float* __restrict__ W,
                                                  const float* __restrict__ dinv,
                                                  __half* __restrict__ out, int n) {
  __shared__ _Float16 Ah[64 * 136];  // [row][k], stride 136 (pad 8)
  __shared__ _Float16 Wt[64 * 136];  // [col][k] transposed
  const int tid = threadIdx.x;
  const int row0 = blockIdx.x * 64;
  for (int i = tid; i < 64 * 32; i += 256) {
    const int r = i >> 5, q = i & 31;
    const int gr = row0 + r;
    float4 v = {0.f, 0.f, 0.f, 0.f};
    if (gr < n) v = reinterpret_cast<const float4*>(x)[(size_t)gr * 32 + q];
    f16x4 hv = {(_Float16)v.x, (_Float16)v.y, (_Float16)v.z, (_Float16)v.w};
    *reinterpret_cast<f16x4*>(&Ah[r * 136 + q * 4]) = hv;
  }
  for (int i = tid; i < 64 * 32; i += 256) {
    const int c = i & 63, k0 = (i >> 6) * 4;
    f16x4 hv = {(_Float16)W[(size_t)(k0 + 0) * 64 + c],
                (_Float16)W[(size_t)(k0 + 1) * 64 + c],
                (_Float16)W[(size_t)(k0 + 2) * 64 + c],
                (_Float16)W[(size_t)(k0 + 3) * 64 + c]};
    *reinterpret_cast<f16x4*>(&Wt[c * 136 + k0]) = hv;
  }
  __syncthreads();
  const int lane = tid & 63;
  const int m = lane & 15, g = lane >> 4;
  const int r0 = (tid >> 6) * 16;
  f32x4 acc0 = {0.f, 0.f, 0.f, 0.f}, acc1 = acc0, acc2 = acc0, acc3 = acc0;
  const _Float16* arow = &Ah[(r0 + m) * 136];
#pragma unroll
  for (int kc = 0; kc < 4; ++kc) {
    const int ko = kc * 32 + g * 4;
    const f16x4 alo = *reinterpret_cast<const f16x4*>(arow + ko);
    const f16x4 ahi = *reinterpret_cast<const f16x4*>(arow + ko + 16);
    const f16x8 a = __builtin_shufflevector(alo, ahi, 0, 1, 2, 3, 4, 5, 6, 7);
    const f16x4 bl0 = *reinterpret_cast<const f16x4*>(&Wt[(0  + m) * 136 + ko]);
    const f16x4 bh0 = *reinterpret_cast<const f16x4*>(&Wt[(0  + m) * 136 + ko + 16]);
    const f16x4 bl1 = *reinterpret_cast<const f16x4*>(&Wt[(16 + m) * 136 + ko]);
    const f16x4 bh1 = *reinterpret_cast<const f16x4*>(&Wt[(16 + m) * 136 + ko + 16]);
    const f16x4 bl2 = *reinterpret_cast<const f16x4*>(&Wt[(32 + m) * 136 + ko]);
    const f16x4 bh2 = *reinterpret_cast<const f16x4*>(&Wt[(32 + m) * 136 + ko + 16]);
    const f16x4 bl3 = *reinterpret_cast<const f16x4*>(&Wt[(48 + m) * 136 + ko]);
    const f16x4 bh3 = *reinterpret_cast<const f16x4*>(&Wt[(48 + m) * 136 + ko + 16]);
    const f16x8 b0 = __builtin_shufflevector(bl0, bh0, 0, 1, 2, 3, 4, 5, 6, 7);
    const f16x8 b1 = __builtin_shufflevector(bl1, bh1, 0, 1, 2, 3, 4, 5, 6, 7);
    const f16x8 b2 = __builtin_shufflevector(bl2, bh2, 0, 1, 2, 3, 4, 5, 6, 7);
    const f16x8 b3 = __builtin_shufflevector(bl3, bh3, 0, 1, 2, 3, 4, 5, 6, 7);
    acc0 = __builtin_amdgcn_mfma_f32_16x16x32_f16(a, b0, acc0, 0, 0, 0);
    acc1 = __builtin_amdgcn_mfma_f32_16x16x32_f16(a, b1, acc1, 0, 0, 0);
    acc2 = __builtin_amdgcn_mfma_f32_16x16x32_f16(a, b2, acc2, 0, 0, 0);
    acc3 = __builtin_amdgcn_mfma_f32_16x16x32_f16(a, b3, acc3, 0, 0, 0);
  }
  _Float16* o16 = reinterpret_cast<_Float16*>(out);
#pragma unroll
  for (int j = 0; j < 4; ++j) {
    const int grow = row0 + r0 + g * 4 + j;
    if (grow < n) {
      const float di = dinv[grow];
      o16[(size_t)grow * 64 + 0  + m] = (_Float16)(acc0[j] * di);
      o16[(size_t)grow * 64 + 16 + m] = (_Float16)(acc1[j] * di);
      o16[(size_t)grow * 64 + 32 + m] = (_Float16)(acc2[j] * di);
      o16[(size_t)grow * 64 + 48 + m] = (_Float16)(acc3[j] * di);
    }
  }
}

// ---------------------------------------------------------------- MFMA gemm, layer 2 (fp16 h, K=64)
__global__ __launch_bounds__(256) void gemm2_mfma(const __half* __restrict__ h,
                                                  const float* __restrict__ W,
                                                  const float* __restrict__ dinv,
                                                  __half* __restrict__ out, int n) {
  __shared__ _Float16 Ah[64 * 72];  // stride 72 (pad 8)
  __shared__ _Float16 Wt[64 * 72];
  const int tid = threadIdx.x;
  const int row0 = blockIdx.x * 64;
  for (int i = tid; i < 64 * 8; i += 256) {
    const int r = i >> 3, q = i & 7;
    const int gr = row0 + r;
    float4 raw = {0.f, 0.f, 0.f, 0.f};
    if (gr < n) raw = reinterpret_cast<const float4*>(h)[(size_t)gr * 8 + q];
    *reinterpret_cast<float4*>(&Ah[r * 72 + q * 8]) = raw;
  }
  for (int i = tid; i < 64 * 16; i += 256) {
    const int c = i & 63, k0 = (i >> 6) * 4;
    f16x4 hv = {(_Float16)W[(size_t)(k0 + 0) * 64 + c],
                (_Float16)W[(size_t)(k0 + 1) * 64 + c],
                (_Float16)W[(size_t)(k0 + 2) * 64 + c],
                (_Float16)W[(size_t)(k0 + 3) * 64 + c]};
    *reinterpret_cast<f16x4*>(&Wt[c * 72 + k0]) = hv;
  }
  __syncthreads();
  const int lane = tid & 63;
  const int m = lane & 15, g = lane >> 4;
  const int r0 = (tid >> 6) * 16;
  f32x4 acc0 = {0.f, 0.f, 0.f, 0.f}, acc1 = acc0, acc2 = acc0, acc3 = acc0;
  const _Float16* arow = &Ah[(r0 + m) * 72];
#pragma unroll
  for (int kc = 0; kc < 2; ++kc) {
    const int ko = kc * 32 + g * 4;
    const f16x4 alo = *reinterpret_cast<const f16x4*>(arow + ko);
    const f16x4 ahi = *reinterpret_cast<const f16x4*>(arow + ko + 16);
    const f16x8 a = __builtin_shufflevector(alo, ahi, 0, 1, 2, 3, 4, 5, 6, 7);
    const f16x4 bl0 = *reinterpret_cast<const f16x4*>(&Wt[(0  + m) * 72 + ko]);
    const f16x4 bh0 = *reinterpret_cast<const f16x4*>(&Wt[(0  + m) * 72 + ko + 16]);
    const f16x4 bl1 = *reinterpret_cast<const f16x4*>(&Wt[(16 + m) * 72 + ko]);
    const f16x4 bh1 = *reinterpret_cast<const f16x4*>(&Wt[(16 + m) * 72 + ko + 16]);
    const f16x4 bl2 = *reinterpret_cast<const f16x4*>(&Wt[(32 + m) * 72 + ko]);
    const f16x4 bh2 = *reinterpret_cast<const f16x4*>(&Wt[(32 + m) * 72 + ko + 16]);
    const f16x4 bl3 = *reinterpret_cast<const f16x4*>(&Wt[(48 + m) * 72 + ko]);
    const f16x4 bh3 = *reinterpret_cast<const f16x4*>(&Wt[(48 + m) * 72 + ko + 16]);
    const f16x8 b0 = __builtin_shufflevector(bl0, bh0, 0, 1, 2, 3, 4, 5, 6, 7);
    const f16x8 b1 = __builtin_shufflevector(bl1, bh1, 0, 1, 2, 3, 4, 5, 6, 7);
    const f16x8 b2 = __builtin_shufflevector(bl2, bh2, 0, 1, 2, 3, 4, 5, 6, 7);
    const f16x8 b3 = __builtin_shufflevector(bl3, bh3, 0, 1, 2, 3, 4, 5, 6, 7);
    acc0 = __builtin_amdgcn_mfma_f32_16x16x32_f16(a, b0, acc0, 0, 0, 0);
    acc1 = __builtin_amdgcn_mfma_f32_16x16x32_f16(a, b1, acc1, 0, 0, 0);
    acc2 = __builtin_amdgcn_mfma_f32_16x16x32_f16(a, b2, acc2, 0, 0, 0);
    acc3 = __builtin_amdgcn_mfma_f32_16x16x32_f16(a, b3, acc3, 0, 0, 0);
  }
  _Float16* o16 = reinterpret_cast<_Float16*>(out);
#pragma unroll
  for (int j = 0; j < 4; ++j) {
    const int grow = row0 + r0 + g * 4 + j;
    if (grow < n) {
      const float di = dinv[grow];
      o16[(size_t)grow * 64 + 0  + m] = (_Float16)(acc0[j] * di);
      o16[(size_t)grow * 64 + 16 + m] = (_Float16)(acc1[j] * di);
      o16[(size_t)grow * 64 + 32 + m] = (_Float16)(acc2[j] * di);
      o16[(size_t)grow * 64 + 48 + m] = (_Float16)(acc3[j] * di);
    }
  }
}

// ---------------------------------------------------------------- pull aggregation (padded rows)
__global__ __launch_bounds__(256) void gather_agg(const int* __restrict__ rowptr,
                                                  const int* __restrict__ rowend,
                                                  const int* __restrict__ colidx,
                                                  const __half2* __restrict__ g2,
                                                  const float* __restrict__ dinv,
                                                  const float* __restrict__ bias,
                                                  __half2* __restrict__ outp, int n) {
  const int lane = threadIdx.x & 63;
  const int node = (blockIdx.x * 256 + threadIdx.x) >> 6;
  if (node >= n) return;
  const int h = lane >> 5;
  const int l = lane & 31;
  const int beg = rowptr[node];
  const int end = rowend[node];
  float2 acc = {0.f, 0.f};
  int e = beg + h;
  for (; e + 30 < end; e += 32) {  // 32 edges/wave-iter
    int s[16];
#pragma unroll
    for (int j = 0; j < 16; ++j) s[j] = colidx[e + 2 * j];
    float2 v[16];
#pragma unroll
    for (int j = 0; j < 16; ++j)
      v[j] = __half22float2(g2[((u32)s[j] << 5) + (u32)l]);
#pragma unroll
    for (int j = 0; j < 16; ++j) {
      acc.x += v[j].x;
      acc.y += v[j].y;
    }
  }
  for (; e + 6 < end; e += 8) {  // exact (rows % 8 == 0)
    const int s0 = colidx[e + 0], s1 = colidx[e + 2];
    const int s2 = colidx[e + 4], s3 = colidx[e + 6];
    const float2 v0 = __half22float2(g2[((u32)s0 << 5) + (u32)l]);
    const float2 v1 = __half22float2(g2[((u32)s1 << 5) + (u32)l]);
    const float2 v2 = __half22float2(g2[((u32)s2 << 5) + (u32)l]);
    const float2 v3 = __half22float2(g2[((u32)s3 << 5) + (u32)l]);
    acc.x += (v0.x + v1.x) + (v2.x + v3.x);
    acc.y += (v0.y + v1.y) + (v2.y + v3.y);
  }
  acc.x += __shfl_xor(acc.x, 32);
  acc.y += __shfl_xor(acc.y, 32);
  const float di = dinv[node];
  const float2 bb = reinterpret_cast<const float2*>(bias)[l];
  const float rx = fmaxf(fmaf(acc.x, di, bb.x), 0.f);
  const float ry = fmaxf(fmaf(acc.y, di, bb.y), 0.f);
  if (h == 0) outp[(size_t)node * 32 + l] = __floats2half2_rn(rx, ry);
}

// ---------------------------------------------------------------- final FC (64 -> 11, fp16 in)
__global__ __launch_bounds__(256) void gemm_fc(const __half* __restrict__ h,
                                               const float* __restrict__ W,
                                               const float* __restrict__ b,
                                               float* __restrict__ out, int n) {
  __shared__ float Wl[772];
  __shared__ float xl[16][68];
  const int tid = threadIdx.x;
  for (int i = tid; i < 772; i += 256) Wl[i] = 0.f;
  __syncthreads();
  for (int i = tid; i < 64 * 11; i += 256) Wl[(i / 11) * 12 + (i % 11)] = W[i];
  const int row00 = blockIdx.x * 64;
  for (int rr = 0; rr < 4; ++rr) {
    const int row0 = row00 + rr * 16;
    __syncthreads();
    if (tid < 128) {
      const int r = tid >> 3, q = tid & 7;
      const int grow = row0 + r;
      if (grow < n) {
        const float4 hv = *reinterpret_cast<const float4*>(
            h + (size_t)grow * 64 + q * 8);
        const __half2* hp = reinterpret_cast<const __half2*>(&hv);
#pragma unroll
        for (int j = 0; j < 4; ++j) {
          const float2 f = __half22float2(hp[j]);
          xl[r][q * 8 + 2 * j + 0] = f.x;
          xl[r][q * 8 + 2 * j + 1] = f.y;
        }
      }
    }
    __syncthreads();
    const int r = tid >> 4, c = tid & 15;
    float acc = 0.f;
#pragma unroll
    for (int k = 0; k < 64; k += 4) {
      acc = fmaf(xl[r][k + 0], Wl[(k + 0) * 12 + c], acc);
      acc = fmaf(xl[r][k + 1], Wl[(k + 1) * 12 + c], acc);
      acc = fmaf(xl[r][k + 2], Wl[(k + 2) * 12 + c], acc);
      acc = fmaf(xl[r][k + 3], Wl[(k + 3) * 12 + c], acc);
    }
    const int grow = row0 + r;
    if (c < 11 && grow < n) out[(size_t)grow * 11 + c] = acc + b[c];
  }
}

// ---------------------------------------------------------------- launch
extern "C" void kernel_launch(void* const* d_in, const int* in_sizes, int n_in,
                              void* d_out, int out_size, void* d_ws, size_t ws_size,
                              hipStream_t stream) {
  const float* x   = (const float*)d_in[0];
  const int*   ei  = (const int*)d_in[1];   // [2, E] int32
  const float* W1  = (const float*)d_in[2];
  const float* b1  = (const float*)d_in[3];
  const float* W2  = (const float*)d_in[4];
  const float* b2  = (const float*)d_in[5];
  const float* Wfc = (const float*)d_in[6];
  const float* bfc = (const float*)d_in[7];
  float* out = (float*)d_out;

  const int n = in_sizes[0] / 128;  // 100000
  const int E = in_sizes[1] / 2;    // 3200000
  const int* src = ei;
  const int* dst = ei + E;
  const int nbk = (n + BKN - 1) >> SH;  // 196 buckets
  const int NE = nbk * NBLK;            // 100352 count entries

  char* ws = (char*)d_ws;
  size_t o = 0;
  auto alloc = [&](size_t bytes) {
    char* p = ws + o;
    o += (bytes + 255) & ~(size_t)255;
    return p;
  };
  float*  dinv   = (float*) alloc((size_t)n * 4);
  int*    rowptr = (int*)   alloc((size_t)n * 4);
  int*    rowend = (int*)   alloc((size_t)n * 4);
  int*    cnt2   = (int*)   alloc((size_t)NE * 4);
  int*    off    = (int*)   alloc((size_t)NE * 4);
  int*    bsum2  = (int*)   alloc(512 * 4);
  u32*    pairs  = (u32*)   alloc((size_t)E * 4);
  int*    colidx = (int*)   alloc(((size_t)E + (size_t)nbk * BKN * 8) * 4);
  __half* B0h    = (__half*)alloc((size_t)(n + 1) * HID * 2);  // g fp16 (+zero row)
  __half* B1h    = (__half*)alloc((size_t)n * HID * 2);        // h1 / h2 fp16
  if (o > ws_size) return;

  const int nb2 = (NE + 255) / 256;     // offset-scan blocks (392)
  const int gblocks = (n + 63) / 64;    // 1563 mfma gemm blocks
  const int fcblocks = (n + 63) / 64;

  // zero row n of g (padding target); rows < n are rewritten every layer
  hipMemsetAsync(B0h + (size_t)n * HID, 0, HID * 2, stream);

  // ---- graph preprocessing (deterministic counting sort; no global atomics)
  count_chunks<<<NBLK, 256, 0, stream>>>(dst, cnt2, E, nbk);
  scan_blocks<<<nb2, 256, 0, stream>>>(cnt2, off, bsum2, NE);
  scan_top<<<1, 512, 0, stream>>>(bsum2, nb2);
  fill_pairs<<<NBLK, 512, 0, stream>>>(src, dst, off, bsum2, pairs, E, nbk);
  bucket_csr<<<nbk, 1024, 0, stream>>>(pairs, off, bsum2, rowptr, rowend, dinv,
                                       colidx, n, nbk, E);

  const int pull_blocks = (n * 64 + 255) / 256;  // one wave per node

  // ---- layer 1
  gemm1_mfma<<<gblocks, 256, 0, stream>>>(x, W1, dinv, B0h, n);
  gather_agg<<<pull_blocks, 256, 0, stream>>>(rowptr, rowend, colidx,
      (const __half2*)B0h, dinv, b1, (__half2*)B1h, n);

  // ---- layer 2
  gemm2_mfma<<<gblocks, 256, 0, stream>>>(B1h, W2, dinv, B0h, n);
  gather_agg<<<pull_blocks, 256, 0, stream>>>(rowptr, rowend, colidx,
      (const __half2*)B0h, dinv, b2, (__half2*)B1h, n);

  // ---- FC head (fp16 activations in, 64 rows/block)
  gemm_fc<<<fcblocks, 256, 0, stream>>>(B1h, Wfc, bfc, out, n);
}